// Round 6
// baseline (545.073 us; speedup 1.0000x reference)
//
#include <hip/hip_runtime.h>

#define BATCH 100000
#define M3 300000            // 3*BATCH rows
#define VECBASE 51200000     // BATCH*512 floats; start of vectors_out region in d_out
#define KP 704               // padded K for Ab/WfT (656 -> 22*32)

typedef float fl4  __attribute__((ext_vector_type(4)));
typedef float f32x4 __attribute__((ext_vector_type(4)));
typedef short s16x8 __attribute__((ext_vector_type(8)));

__device__ __forceinline__ short f2bf(float f) {
  unsigned int u = __float_as_uint(f);
  u += 0x7fffu + ((u >> 16) & 1u);
  return (short)(u >> 16);
}
__device__ __forceinline__ float bf2f(short s) {
  return __uint_as_float(((unsigned int)(unsigned short)s) << 16);
}
__device__ __forceinline__ s16x8 pack8(fl4 a, fl4 b) {
  s16x8 o;
  o[0] = f2bf(a[0]); o[1] = f2bf(a[1]); o[2] = f2bf(a[2]); o[3] = f2bf(a[3]);
  o[4] = f2bf(b[0]); o[5] = f2bf(b[1]); o[6] = f2bf(b[2]); o[7] = f2bf(b[3]);
  return o;
}
__device__ __forceinline__ void glds16(const void* g, void* l) {
  __builtin_amdgcn_global_load_lds((const __attribute__((address_space(1))) void*)g,
                                   (__attribute__((address_space(3))) void*)l, 16, 0, 0);
}
// swizzled chunk offset within a 64-B (32-short) row: chunk ck stored at ck^((row>>1)&3)
#define SWOFF(row, ck) (((row) << 5) + ((((ck) ^ (((row) >> 1) & 3))) << 3))

// ---------------------------------------------------------------------------
// K0: weight prep (bf16 transposes, one-shot)
__global__ __launch_bounds__(256) void prep_w(
    const float* __restrict__ Wh, const float* __restrict__ Wcp,
    const float* __restrict__ Wu, const float* __restrict__ Wf,
    const float* __restrict__ Wg, short* __restrict__ WB1,
    short* __restrict__ WuTp, short* __restrict__ WfT, short* __restrict__ WgT) {
  int gid = blockIdx.x * 256 + threadIdx.x;
  if (gid < 20480) {                       // WB1 [160][128]
    int n = gid >> 7, k = gid & 127;
    WB1[gid] = f2bf(n < 128 ? Wh[k * 128 + n] : Wcp[k * 32 + (n - 128)]);
  } else if (gid < 40960) {                // WuTp [128][160]
    int i = gid - 20480;
    int o = i / 160, k = i - o * 160;
    WuTp[i] = k < 144 ? f2bf(Wu[k * 128 + o]) : (short)0;
  } else if (gid < 40960 + 512 * KP) {     // WfT [512][704]
    int i = gid - 40960;
    int n = i / KP, k = i - n * KP;
    WfT[i] = k < 656 ? f2bf(Wf[k * 512 + n]) : (short)0;
  } else if (gid < 40960 + 512 * KP + 65536) {  // WgT [128][512]
    int i = gid - (40960 + 512 * KP);
    int n = i >> 9, k = i & 511;
    WgT[i] = f2bf(Wg[k * 128 + n]);
  }
}

// ---------------------------------------------------------------------------
// K1: fused geo GEMM1 + cross + norms + feats->bf16 copy.
// Per block: 64 b's. GEMM D[192][160]; cross -> cols 128..143; norms -> Ab
// cols 512..655 (+zeros to 703); Vcat [row][160] bf16 -> d_out scratch;
// feats rows -> Ab cols 0..511 (bf16).
__global__ __launch_bounds__(256) void geo_gemm1(
    const float* __restrict__ vecs, const float* __restrict__ feats,
    const short* __restrict__ WB1, short* __restrict__ Vcat,
    short* __restrict__ Ab) {
  __shared__ __align__(16) short U[192 * 160];
  const int t = threadIdx.x;
  const int b0 = blockIdx.x * 64;
  const int row0 = blockIdx.x * 192;

#pragma unroll
  for (int it = 0; it < 24; ++it) {
    int fj = (it * 256 + t) * 4;
    int bl = fj / 384;
    int rem = fj - bl * 384;
    int v = rem / 3, c = rem - v * 3;
    fl4 val = (fl4){0.f, 0.f, 0.f, 0.f};
    int b = b0 + bl;
    if (b < BATCH) val = *reinterpret_cast<const fl4*>(&vecs[(size_t)b * 384 + rem]);
#pragma unroll
    for (int e = 0; e < 4; ++e) {
      int row = bl * 3 + c;
      int off = (row << 8) + (v << 1);
      *(short*)((char*)U + (off ^ ((row & 7) << 4))) = f2bf(val[e]);
      if (++c == 3) { c = 0; ++v; }
    }
  }
  __syncthreads();

  const int lane = t & 63, wv = t >> 6;
  const int wr = wv >> 1, wc = wv & 1;
  const int lr = lane & 15, lk = lane >> 4;
  f32x4 acc[6][5];
#pragma unroll
  for (int i = 0; i < 6; ++i)
#pragma unroll
    for (int j = 0; j < 5; ++j) acc[i][j] = (f32x4){0.f, 0.f, 0.f, 0.f};

#pragma unroll
  for (int kk = 0; kk < 4; ++kk) {
    s16x8 af[6], bq[5];
#pragma unroll
    for (int mi = 0; mi < 6; ++mi) {
      int row = wr * 96 + mi * 16 + lr;
      int off = (row << 8) + (kk << 6) + (lk << 4);
      af[mi] = *(const s16x8*)((const char*)U + (off ^ ((row & 7) << 4)));
    }
#pragma unroll
    for (int ni = 0; ni < 5; ++ni)
      bq[ni] = *reinterpret_cast<const s16x8*>(
          &WB1[(wc * 80 + ni * 16 + lr) * 128 + (kk << 5) + (lk << 3)]);
#pragma unroll
    for (int mi = 0; mi < 6; ++mi)
#pragma unroll
      for (int ni = 0; ni < 5; ++ni)
        acc[mi][ni] = __builtin_amdgcn_mfma_f32_16x16x32_bf16(af[mi], bq[ni], acc[mi][ni], 0, 0, 0);
  }
  __syncthreads();

#pragma unroll
  for (int mi = 0; mi < 6; ++mi)
#pragma unroll
    for (int ni = 0; ni < 5; ++ni) {
      int col = wc * 80 + ni * 16 + lr;
#pragma unroll
      for (int r = 0; r < 4; ++r) {
        int row = wr * 96 + mi * 16 + lk * 4 + r;
        U[row * 160 + col] = f2bf(acc[mi][ni][r]);
      }
    }
  __syncthreads();

  {  // cross: 4 threads per b, 4 p's each
    int bl = t >> 2, pj = t & 3;
    int gb = b0 + bl;
    float shcp[4];
#pragma unroll
    for (int q = 0; q < 4; ++q) {
      int p = pj * 4 + q;
      float ax = bf2f(U[(bl * 3 + 0) * 160 + 128 + p]);
      float ay = bf2f(U[(bl * 3 + 1) * 160 + 128 + p]);
      float az = bf2f(U[(bl * 3 + 2) * 160 + 128 + p]);
      float bx = bf2f(U[(bl * 3 + 0) * 160 + 144 + p]);
      float by = bf2f(U[(bl * 3 + 1) * 160 + 144 + p]);
      float bz = bf2f(U[(bl * 3 + 2) * 160 + 144 + p]);
      float cx = ay * bz - az * by;
      float cy = az * bx - ax * bz;
      float cz = ax * by - ay * bx;
      U[(bl * 3 + 0) * 160 + 128 + p] = f2bf(cx);
      U[(bl * 3 + 1) * 160 + 128 + p] = f2bf(cy);
      U[(bl * 3 + 2) * 160 + 128 + p] = f2bf(cz);
      U[(bl * 3 + 0) * 160 + 144 + p] = 0;
      U[(bl * 3 + 1) * 160 + 144 + p] = 0;
      U[(bl * 3 + 2) * 160 + 144 + p] = 0;
      shcp[q] = sqrtf(fmaxf(cx * cx + cy * cy + cz * cz, 1e-8f));
    }
    if (gb < BATCH) {
#pragma unroll
      for (int q = 0; q < 4; ++q)
        Ab[(size_t)gb * KP + 512 + 128 + pj * 4 + q] = f2bf(shcp[q]);
#pragma unroll
      for (int z = 0; z < 12; ++z)
        Ab[(size_t)gb * KP + 512 + 144 + pj * 12 + z] = 0;
    }
  }
  {  // norms k<128 -> Ab cols 512..639
    int bl = t >> 2, kq = t & 3;
    int gb = b0 + bl;
    if (gb < BATCH) {
#pragma unroll
      for (int j = 0; j < 4; ++j) {
        int k = kq * 32 + j * 8;
        s16x8 r0 = *(const s16x8*)&U[(bl * 3 + 0) * 160 + k];
        s16x8 r1 = *(const s16x8*)&U[(bl * 3 + 1) * 160 + k];
        s16x8 r2 = *(const s16x8*)&U[(bl * 3 + 2) * 160 + k];
        s16x8 o;
#pragma unroll
        for (int e = 0; e < 8; ++e) {
          float x = bf2f(r0[e]), y = bf2f(r1[e]), z = bf2f(r2[e]);
          o[e] = f2bf(sqrtf(fmaxf(x * x + y * y + z * z, 1e-8f)));
        }
        *(s16x8*)&Ab[(size_t)gb * KP + 512 + k] = o;
      }
    }
  }
  __syncthreads();
  {  // Vcat bulk copy
    const char* src = (const char*)U;
    char* dst = (char*)Vcat + (size_t)row0 * 320;
    size_t lim = 96000000ULL - (size_t)row0 * 320;
#pragma unroll
    for (int j = 0; j < 15; ++j) {
      int byte = (j * 256 + t) * 16;
      if ((size_t)byte < lim)
        *(s16x8*)(dst + byte) = *(const s16x8*)(src + byte);
    }
  }
  {  // feats -> Ab[:,0:512) bf16 (streaming, 64 rows x 512)
#pragma unroll
    for (int j = 0; j < 16; ++j) {
      int idx = (j * 256 + t) * 8;        // float index in [0, 32768)
      int bl = idx >> 9, kk = idx & 511;
      int gb = b0 + bl;
      if (gb < BATCH) {
        fl4 v0 = *(const fl4*)&feats[(size_t)gb * 512 + kk];
        fl4 v1 = *(const fl4*)&feats[(size_t)gb * 512 + kk + 4];
        *(s16x8*)&Ab[(size_t)gb * KP + kk] = pack8(v0, v1);
      }
    }
  }
}

// ---------------------------------------------------------------------------
// K2: Vu GEMM. (unchanged)
__global__ __launch_bounds__(256) void geo_gemm2(
    const short* __restrict__ Vcat, const short* __restrict__ WuTp,
    short* __restrict__ Vub) {
  __shared__ __align__(16) short Al[128 * 192];
  const int t = threadIdx.x;
  const int row0 = blockIdx.x << 7;
#pragma unroll
  for (int it = 0; it < 10; ++it) {
    int idx = it * 256 + t;
    int r = idx / 20, ch = idx - r * 20;
    int grow = row0 + r;
    s16x8 q = (s16x8){0, 0, 0, 0, 0, 0, 0, 0};
    if (grow < M3) q = *reinterpret_cast<const s16x8*>(&Vcat[(size_t)grow * 160 + ch * 8]);
    int off = r * 384 + ch * 16;
    *(s16x8*)((char*)Al + (off ^ ((r & 7) << 4))) = q;
  }
  __syncthreads();

  const int lane = t & 63, wv = t >> 6;
  const int wr = wv >> 1, wc = wv & 1;
  const int lr = lane & 15, lk = lane >> 4;
  f32x4 acc[4][4];
#pragma unroll
  for (int i = 0; i < 4; ++i)
#pragma unroll
    for (int j = 0; j < 4; ++j) acc[i][j] = (f32x4){0.f, 0.f, 0.f, 0.f};

#pragma unroll
  for (int kk = 0; kk < 5; ++kk) {
    s16x8 af[4], bq[4];
#pragma unroll
    for (int mi = 0; mi < 4; ++mi) {
      int row = wr * 64 + mi * 16 + lr;
      int off = row * 384 + (kk << 6) + (lk << 4);
      af[mi] = *(const s16x8*)((const char*)Al + (off ^ ((row & 7) << 4)));
    }
#pragma unroll
    for (int ni = 0; ni < 4; ++ni)
      bq[ni] = *reinterpret_cast<const s16x8*>(
          &WuTp[(wc * 64 + ni * 16 + lr) * 160 + (kk << 5) + (lk << 3)]);
#pragma unroll
    for (int mi = 0; mi < 4; ++mi)
#pragma unroll
      for (int ni = 0; ni < 4; ++ni)
        acc[mi][ni] = __builtin_amdgcn_mfma_f32_16x16x32_bf16(af[mi], bq[ni], acc[mi][ni], 0, 0, 0);
  }
#pragma unroll
  for (int mi = 0; mi < 4; ++mi)
#pragma unroll
    for (int ni = 0; ni < 4; ++ni) {
      int col = wc * 64 + ni * 16 + lr;
#pragma unroll
      for (int r = 0; r < 4; ++r) {
        int row = row0 + wr * 64 + mi * 16 + lk * 4 + r;
        if (row < M3) Vub[(size_t)row * 128 + col] = f2bf(acc[mi][ni][r]);
      }
    }
}

// ---------------------------------------------------------------------------
// K3: feats_out = silu(Ab @ Wf + bf).  M=100000, K=704 (zero-padded), N=512.
// m97 structure: single-buffered LDS, both operands via global_load_lds width-16,
// per K-step {sync; 4x glds16; sync(drain); 8x ds_read_b128; 16 MFMA}.
__global__ __launch_bounds__(256) void gemm_feats(
    const short* __restrict__ Ab, const short* __restrict__ WfT,
    const float* __restrict__ bfv, float* __restrict__ out) {
  const int bid = blockIdx.x;
  const int swz = (bid & 7) * 391 + (bid >> 3);
  const int mt = swz >> 2, nt = swz & 3;
  const int row0 = mt << 7, n0 = nt << 7;
  const int t = threadIdx.x;
  const int lane = t & 63, wv = t >> 6;
  const int wr = wv >> 1, wc = wv & 1;
  const int lr = lane & 15, lk = lane >> 4;

  __shared__ __align__(16) short As[128 * 32];   // 8 KB, linear [row][32k]
  __shared__ __align__(16) short Bs[128 * 32];   // 8 KB

  // staging: thread t stages rows srow0 and 64+srow0, 16B chunk ck
  const int srow0 = t >> 2, ck = t & 3;
  const short* ap1 = &Ab[(size_t)min(row0 + srow0, BATCH - 1) * KP + ck * 8];
  const short* ap2 = &Ab[(size_t)min(row0 + 64 + srow0, BATCH - 1) * KP + ck * 8];
  const short* bp1 = &WfT[(size_t)(n0 + srow0) * KP + ck * 8];
  const short* bp2 = &WfT[(size_t)(n0 + 64 + srow0) * KP + ck * 8];

  f32x4 acc[4][4];
#pragma unroll
  for (int i = 0; i < 4; ++i)
#pragma unroll
    for (int j = 0; j < 4; ++j) acc[i][j] = (f32x4){0.f, 0.f, 0.f, 0.f};

  for (int ks = 0; ks < 22; ++ks) {
    const int k0 = ks << 5;
    __syncthreads();
    glds16(ap1 + k0, &As[t * 8]);
    glds16(ap2 + k0, &As[2048 + t * 8]);
    glds16(bp1 + k0, &Bs[t * 8]);
    glds16(bp2 + k0, &Bs[2048 + t * 8]);
    __syncthreads();
    s16x8 af[4], bq[4];
#pragma unroll
    for (int mi = 0; mi < 4; ++mi)
      af[mi] = *(const s16x8*)&As[(wr * 64 + mi * 16 + lr) * 32 + lk * 8];
#pragma unroll
    for (int ni = 0; ni < 4; ++ni)
      bq[ni] = *(const s16x8*)&Bs[(wc * 64 + ni * 16 + lr) * 32 + lk * 8];
#pragma unroll
    for (int mi = 0; mi < 4; ++mi)
#pragma unroll
      for (int ni = 0; ni < 4; ++ni)
        acc[mi][ni] = __builtin_amdgcn_mfma_f32_16x16x32_bf16(af[mi], bq[ni], acc[mi][ni], 0, 0, 0);
  }

#pragma unroll
  for (int ni = 0; ni < 4; ++ni) {
    int col = n0 + wc * 64 + ni * 16 + lr;
    float bb = bfv[col];
#pragma unroll
    for (int mi = 0; mi < 4; ++mi) {
      int rbase = row0 + wr * 64 + mi * 16 + lk * 4;
#pragma unroll
      for (int rr = 0; rr < 4; ++rr) {
        int gr = rbase + rr;
        if (gr < BATCH) {
          float x = acc[mi][ni][rr] + bb;
          out[(size_t)gr * 512 + col] = x / (1.f + __expf(-x));
        }
      }
    }
  }
}

// ---------------------------------------------------------------------------
// K4: gating GEMM + sigmoid*Vub -> vectors_out f32. (unchanged from R5)
__global__ __launch_bounds__(256) void gemm_gate(
    const float* __restrict__ fo, const short* __restrict__ WgT,
    const float* __restrict__ bg, const short* __restrict__ Vub,
    float* __restrict__ out) {
  const int bid = blockIdx.x;
  const int xcd = bid & 7, bidx = bid >> 3;
  const int swz = (xcd < 6 ? xcd * 98 : 6 * 98 + (xcd - 6) * 97) + bidx;
  const int row0 = swz << 7;
  const int t = threadIdx.x;
  const int lane = t & 63, wv = t >> 6;
  const int wr = wv >> 1, wc = wv & 1;
  const int lr = lane & 15, lk = lane >> 4;

  __shared__ __align__(16) short Al[2][128 * 32];
  __shared__ __align__(16) short Bl[2][128 * 32];

  const int ar = t >> 1, h = t & 1;
  const size_t arowc = (size_t)min(row0 + ar, BATCH - 1);
  const float* aFp = &fo[arowc * 512 + h * 16];
  const int aw1 = SWOFF(ar, 2 * h), aw2 = SWOFF(ar, 2 * h + 1);

  const int bc = (lane & 3) ^ ((lane >> 3) & 3);
  const short* bSrc0 = &WgT[(size_t)((wv * 2 + 0) * 16 + (lane >> 2)) * 512 + bc * 8];
  const short* bSrc1 = &WgT[(size_t)((wv * 2 + 1) * 16 + (lane >> 2)) * 512 + bc * 8];

  f32x4 acc[4][4];
#pragma unroll
  for (int i = 0; i < 4; ++i)
#pragma unroll
    for (int j = 0; j < 4; ++j) acc[i][j] = (f32x4){0.f, 0.f, 0.f, 0.f};

  fl4 frA[4], frB[4];

  auto issueA = [&](int ks, fl4* fr) {
    const int k0 = ks << 5;
#pragma unroll
    for (int j = 0; j < 4; ++j) fr[j] = *reinterpret_cast<const fl4*>(aFp + k0 + j * 4);
  };
  auto commitA = [&](int buf, const fl4* fr) {
    *(s16x8*)&Al[buf][aw1] = pack8(fr[0], fr[1]);
    *(s16x8*)&Al[buf][aw2] = pack8(fr[2], fr[3]);
  };
  auto gldsB = [&](int ks, int buf) {
    const int k0 = ks << 5;
    glds16(bSrc0 + k0, &Bl[buf][(wv * 2 + 0) * 512]);
    glds16(bSrc1 + k0, &Bl[buf][(wv * 2 + 1) * 512]);
  };
  auto compute = [&](int buf) {
    s16x8 af[4], bq[4];
#pragma unroll
    for (int mi = 0; mi < 4; ++mi) {
      int rw = wr * 64 + mi * 16 + lr;
      af[mi] = *(const s16x8*)&Al[buf][SWOFF(rw, lk)];
    }
#pragma unroll
    for (int ni = 0; ni < 4; ++ni) {
      int rw = wc * 64 + ni * 16 + lr;
      bq[ni] = *(const s16x8*)&Bl[buf][SWOFF(rw, lk)];
    }
#pragma unroll
    for (int mi = 0; mi < 4; ++mi)
#pragma unroll
      for (int ni = 0; ni < 4; ++ni)
        acc[mi][ni] = __builtin_amdgcn_mfma_f32_16x16x32_bf16(af[mi], bq[ni], acc[mi][ni], 0, 0, 0);
  };

  issueA(0, frA);
  commitA(0, frA);
  gldsB(0, 0);
  issueA(1, frB);
  __syncthreads();

  for (int ks = 0; ks < 16; ks += 2) {
    if (ks + 2 < 16) issueA(ks + 2, frA);
    if (ks + 1 < 16) { commitA(1, frB); gldsB(ks + 1, 1); }
    compute(0);
    __syncthreads();
    if (ks + 3 < 16) issueA(ks + 3, frB);
    if (ks + 2 < 16) { commitA(0, frA); gldsB(ks + 2, 0); }
    if (ks + 1 < 16) compute(1);
    __syncthreads();
  }

#pragma unroll
  for (int ni = 0; ni < 4; ++ni) {
    int col = wc * 64 + ni * 16 + lr;
    float bb = bg[col];
#pragma unroll
    for (int mi = 0; mi < 4; ++mi) {
      int rbase = row0 + wr * 64 + mi * 16 + lk * 4;
#pragma unroll
      for (int rr = 0; rr < 4; ++rr) {
        int gr = rbase + rr;
        if (gr < BATCH) {
          float x = acc[mi][ni][rr] + bb;
          float gate = 1.f / (1.f + __expf(-x));
          size_t vb = (size_t)(3 * gr) * 128 + col;
          float* po = &out[VECBASE + ((size_t)gr * 128 + col) * 3];
          po[0] = gate * bf2f(Vub[vb]);
          po[1] = gate * bf2f(Vub[vb + 128]);
          po[2] = gate * bf2f(Vub[vb + 256]);
        }
      }
    }
  }
}

// ---------------------------------------------------------------------------
extern "C" void kernel_launch(void* const* d_in, const int* in_sizes, int n_in,
                              void* d_out, int out_size, void* d_ws, size_t ws_size,
                              hipStream_t stream) {
  const float* feats = (const float*)d_in[0];
  const float* vecs  = (const float*)d_in[1];
  const float* Wh    = (const float*)d_in[2];
  const float* Wcp   = (const float*)d_in[3];
  const float* Wu    = (const float*)d_in[4];
  const float* Wf    = (const float*)d_in[5];
  const float* bfv   = (const float*)d_in[6];
  const float* Wg    = (const float*)d_in[7];
  const float* bg    = (const float*)d_in[8];
  float* out = (float*)d_out;

  char* ws = (char*)d_ws;
  short* Ab   = (short*)ws;                                // 100000*704*2 = 140,800,000
  short* Vub  = (short*)(ws + 140800000);                  // 300000*128*2 =  76,800,000
  short* WfT  = (short*)(ws + 217600000);                  // 512*704*2    =     720,896
  short* WgT  = (short*)(ws + 218320896);                  // 128*512*2    =     131,072
  short* WB1  = (short*)(ws + 218451968);                  //                     40,960
  short* WuTp = (short*)(ws + 218492928);                  //                     40,960

  short* Vcat = (short*)d_out;  // [3B][160] bf16 in dead feats region (96 MB)

  hipLaunchKernelGGL(prep_w,     dim3(1824), dim3(256), 0, stream, Wh, Wcp, Wu, Wf, Wg, WB1, WuTp, WfT, WgT);
  hipLaunchKernelGGL(geo_gemm1,  dim3(1563), dim3(256), 0, stream, vecs, feats, WB1, Vcat, Ab);
  hipLaunchKernelGGL(geo_gemm2,  dim3(2344), dim3(256), 0, stream, Vcat, WuTp, Vub);
  hipLaunchKernelGGL(gemm_feats, dim3(3128), dim3(256), 0, stream, Ab, WfT, bfv, out);
  hipLaunchKernelGGL(gemm_gate,  dim3(782),  dim3(256), 0, stream, out, WgT, bg, Vub, out);
}

// Round 7
// 532.136 us; speedup vs baseline: 1.0243x; 1.0243x over previous
//
#include <hip/hip_runtime.h>

#define BATCH 100000
#define M3 300000            // 3*BATCH rows
#define VECBASE 51200000     // BATCH*512 floats; start of vectors_out region in d_out
#define KP 704               // padded K for Ab/WfT (656 -> 22*32)

typedef float fl4  __attribute__((ext_vector_type(4)));
typedef float f32x4 __attribute__((ext_vector_type(4)));
typedef short s16x8 __attribute__((ext_vector_type(8)));

__device__ __forceinline__ short f2bf(float f) {
  unsigned int u = __float_as_uint(f);
  u += 0x7fffu + ((u >> 16) & 1u);
  return (short)(u >> 16);
}
__device__ __forceinline__ float bf2f(short s) {
  return __uint_as_float(((unsigned int)(unsigned short)s) << 16);
}
__device__ __forceinline__ s16x8 pack8(fl4 a, fl4 b) {
  s16x8 o;
  o[0] = f2bf(a[0]); o[1] = f2bf(a[1]); o[2] = f2bf(a[2]); o[3] = f2bf(a[3]);
  o[4] = f2bf(b[0]); o[5] = f2bf(b[1]); o[6] = f2bf(b[2]); o[7] = f2bf(b[3]);
  return o;
}
__device__ __forceinline__ void glds16(const void* g, void* l) {
  __builtin_amdgcn_global_load_lds((const __attribute__((address_space(1))) void*)g,
                                   (__attribute__((address_space(3))) void*)l, 16, 0, 0);
}

// ---------------------------------------------------------------------------
// K0: prep. (a) feats -> Ab[:,0:512) bf16 (streaming, full-occupancy);
//          (b) weight transposes to bf16.
__global__ __launch_bounds__(256) void prep_w(
    const float* __restrict__ feats, const float* __restrict__ Wh,
    const float* __restrict__ Wcp, const float* __restrict__ Wu,
    const float* __restrict__ Wf, const float* __restrict__ Wg,
    short* __restrict__ Ab, short* __restrict__ WB1, short* __restrict__ WuTp,
    short* __restrict__ WfT, short* __restrict__ WgT) {
  const int tid = blockIdx.x * 256 + threadIdx.x;
  const int stride = gridDim.x * 256;
  // feats: 100000*512 / 8 = 6.4M chunks of 8 floats
  for (int i = tid; i < 6400000; i += stride) {
    int b = i >> 6, kk = (i & 63) * 8;
    fl4 v0 = *reinterpret_cast<const fl4*>(&feats[(size_t)b * 512 + kk]);
    fl4 v1 = *reinterpret_cast<const fl4*>(&feats[(size_t)b * 512 + kk + 4]);
    *(s16x8*)&Ab[(size_t)b * KP + kk] = pack8(v0, v1);
  }
  // weights: 466,944 scalar elements
  for (int gid = tid; gid < 466944; gid += stride) {
    if (gid < 20480) {                       // WB1 [160][128]
      int n = gid >> 7, k = gid & 127;
      WB1[gid] = f2bf(n < 128 ? Wh[k * 128 + n] : Wcp[k * 32 + (n - 128)]);
    } else if (gid < 40960) {                // WuTp [128][160]
      int i = gid - 20480;
      int o = i / 160, k = i - o * 160;
      WuTp[i] = k < 144 ? f2bf(Wu[k * 128 + o]) : (short)0;
    } else if (gid < 401408) {               // WfT [512][704]
      int i = gid - 40960;
      int n = i / KP, k = i - n * KP;
      WfT[i] = k < 656 ? f2bf(Wf[k * 512 + n]) : (short)0;
    } else {                                 // WgT [128][512]
      int i = gid - 401408;
      int n = i >> 9, k = i & 511;
      WgT[i] = f2bf(Wg[k * 128 + n]);
    }
  }
}

// ---------------------------------------------------------------------------
// K1: geo_fused. Per block (64 b's = 192 rows):
//   GEMM1 D[192][160] = A[192][128] @ WB1^T   (A staged from vecs)
//   result -> U (pitch 168 shorts), cross -> cols 128..143 (144..159 zero),
//   norms -> Ab cols 512..655 (+ zeros 656..703),
//   GEMM2 Vu[192][128] = U[192][160] @ WuTp^T -> Vub bf16.
__global__ __launch_bounds__(256) void geo_fused(
    const float* __restrict__ vecs, const short* __restrict__ WB1,
    const short* __restrict__ WuTp, short* __restrict__ Ab,
    short* __restrict__ Vub) {
  __shared__ __align__(16) short U[192 * 168];   // 64,512 B
  const int t = threadIdx.x;
  const int b0 = blockIdx.x * 64;
  const int row0 = blockIdx.x * 192;

  // ---- stage A [192][128] bf16 (pitch 256B, XOR swizzle) into U's first 48KB
#pragma unroll
  for (int it = 0; it < 24; ++it) {
    int fj = (it * 256 + t) * 4;
    int bl = fj / 384;
    int rem = fj - bl * 384;
    int v = rem / 3, c = rem - v * 3;
    fl4 val = (fl4){0.f, 0.f, 0.f, 0.f};
    int b = b0 + bl;
    if (b < BATCH) val = *reinterpret_cast<const fl4*>(&vecs[(size_t)b * 384 + rem]);
#pragma unroll
    for (int e = 0; e < 4; ++e) {
      int row = bl * 3 + c;
      int off = (row << 8) + (v << 1);
      *(short*)((char*)U + (off ^ ((row & 7) << 4))) = f2bf(val[e]);
      if (++c == 3) { c = 0; ++v; }
    }
  }
  __syncthreads();

  const int lane = t & 63, wv = t >> 6;
  const int wr = wv >> 1, wc = wv & 1;
  const int lr = lane & 15, lk = lane >> 4;

  {  // ---- GEMM1
    f32x4 acc[6][5];
#pragma unroll
    for (int i = 0; i < 6; ++i)
#pragma unroll
      for (int j = 0; j < 5; ++j) acc[i][j] = (f32x4){0.f, 0.f, 0.f, 0.f};
#pragma unroll
    for (int kk = 0; kk < 4; ++kk) {
      s16x8 af[6], bq[5];
#pragma unroll
      for (int mi = 0; mi < 6; ++mi) {
        int row = wr * 96 + mi * 16 + lr;
        int off = (row << 8) + (kk << 6) + (lk << 4);
        af[mi] = *(const s16x8*)((const char*)U + (off ^ ((row & 7) << 4)));
      }
#pragma unroll
      for (int ni = 0; ni < 5; ++ni)
        bq[ni] = *reinterpret_cast<const s16x8*>(
            &WB1[(wc * 80 + ni * 16 + lr) * 128 + (kk << 5) + (lk << 3)]);
#pragma unroll
      for (int mi = 0; mi < 6; ++mi)
#pragma unroll
        for (int ni = 0; ni < 5; ++ni)
          acc[mi][ni] = __builtin_amdgcn_mfma_f32_16x16x32_bf16(af[mi], bq[ni], acc[mi][ni], 0, 0, 0);
    }
    __syncthreads();   // staging reads done; U becomes result [192][168-pitch]
#pragma unroll
    for (int mi = 0; mi < 6; ++mi)
#pragma unroll
      for (int ni = 0; ni < 5; ++ni) {
        int col = wc * 80 + ni * 16 + lr;
#pragma unroll
        for (int r = 0; r < 4; ++r) {
          int row = wr * 96 + mi * 16 + lk * 4 + r;
          U[row * 168 + col] = f2bf(acc[mi][ni][r]);
        }
      }
  }
  __syncthreads();

  {  // ---- cross: 4 threads per b, 4 p's each; sh(cp) -> Ab cols 640..655, zeros 656..703
    int bl = t >> 2, pj = t & 3;
    int gb = b0 + bl;
    float shcp[4];
#pragma unroll
    for (int q = 0; q < 4; ++q) {
      int p = pj * 4 + q;
      float ax = bf2f(U[(bl * 3 + 0) * 168 + 128 + p]);
      float ay = bf2f(U[(bl * 3 + 1) * 168 + 128 + p]);
      float az = bf2f(U[(bl * 3 + 2) * 168 + 128 + p]);
      float bx = bf2f(U[(bl * 3 + 0) * 168 + 144 + p]);
      float by = bf2f(U[(bl * 3 + 1) * 168 + 144 + p]);
      float bz = bf2f(U[(bl * 3 + 2) * 168 + 144 + p]);
      float cx = ay * bz - az * by;
      float cy = az * bx - ax * bz;
      float cz = ax * by - ay * bx;
      U[(bl * 3 + 0) * 168 + 128 + p] = f2bf(cx);
      U[(bl * 3 + 1) * 168 + 128 + p] = f2bf(cy);
      U[(bl * 3 + 2) * 168 + 128 + p] = f2bf(cz);
      U[(bl * 3 + 0) * 168 + 144 + p] = 0;
      U[(bl * 3 + 1) * 168 + 144 + p] = 0;
      U[(bl * 3 + 2) * 168 + 144 + p] = 0;
      shcp[q] = sqrtf(fmaxf(cx * cx + cy * cy + cz * cz, 1e-8f));
    }
    if (gb < BATCH) {
#pragma unroll
      for (int q = 0; q < 4; ++q)
        Ab[(size_t)gb * KP + 512 + 128 + pj * 4 + q] = f2bf(shcp[q]);
#pragma unroll
      for (int z = 0; z < 12; ++z)
        Ab[(size_t)gb * KP + 512 + 144 + pj * 12 + z] = 0;
    }
  }
  {  // ---- norms k<128 -> Ab cols 512..639 (disjoint from cross cols; no barrier)
    int bl = t >> 2, kq = t & 3;
    int gb = b0 + bl;
    if (gb < BATCH) {
#pragma unroll
      for (int j = 0; j < 4; ++j) {
        int k = kq * 32 + j * 8;
        s16x8 r0 = *(const s16x8*)&U[(bl * 3 + 0) * 168 + k];
        s16x8 r1 = *(const s16x8*)&U[(bl * 3 + 1) * 168 + k];
        s16x8 r2 = *(const s16x8*)&U[(bl * 3 + 2) * 168 + k];
        s16x8 o;
#pragma unroll
        for (int e = 0; e < 8; ++e) {
          float x = bf2f(r0[e]), y = bf2f(r1[e]), z = bf2f(r2[e]);
          o[e] = f2bf(sqrtf(fmaxf(x * x + y * y + z * z, 1e-8f)));
        }
        *(s16x8*)&Ab[(size_t)gb * KP + 512 + k] = o;
      }
    }
  }
  __syncthreads();   // cross writes visible to GEMM2

  {  // ---- GEMM2: Vu[192][128] = U[192][160] @ WuTp^T
    f32x4 acc2[6][4];
#pragma unroll
    for (int i = 0; i < 6; ++i)
#pragma unroll
      for (int j = 0; j < 4; ++j) acc2[i][j] = (f32x4){0.f, 0.f, 0.f, 0.f};
#pragma unroll
    for (int kk = 0; kk < 5; ++kk) {
      s16x8 af[6], bq[4];
#pragma unroll
      for (int mi = 0; mi < 6; ++mi) {
        int row = wr * 96 + mi * 16 + lr;
        af[mi] = *(const s16x8*)&U[row * 168 + (kk << 5) + (lk << 3)];
      }
#pragma unroll
      for (int ni = 0; ni < 4; ++ni)
        bq[ni] = *reinterpret_cast<const s16x8*>(
            &WuTp[(wc * 64 + ni * 16 + lr) * 160 + (kk << 5) + (lk << 3)]);
#pragma unroll
      for (int mi = 0; mi < 6; ++mi)
#pragma unroll
        for (int ni = 0; ni < 4; ++ni)
          acc2[mi][ni] = __builtin_amdgcn_mfma_f32_16x16x32_bf16(af[mi], bq[ni], acc2[mi][ni], 0, 0, 0);
    }
#pragma unroll
    for (int mi = 0; mi < 6; ++mi)
#pragma unroll
      for (int ni = 0; ni < 4; ++ni) {
        int col = wc * 64 + ni * 16 + lr;
#pragma unroll
        for (int r = 0; r < 4; ++r) {
          int row = row0 + wr * 96 + mi * 16 + lk * 4 + r;
          if (row < M3) Vub[(size_t)row * 128 + col] = f2bf(acc2[mi][ni][r]);
        }
      }
  }
}

// ---------------------------------------------------------------------------
// K2: feats_out = silu(Ab @ Wf + bf) -> out f32 AND fob bf16.
// m97 structure: 16KB LDS, both operands via global_load_lds width-16.
__global__ __launch_bounds__(256) void gemm_feats(
    const short* __restrict__ Ab, const short* __restrict__ WfT,
    const float* __restrict__ bfv, float* __restrict__ out,
    short* __restrict__ fob) {
  const int bid = blockIdx.x;
  const int swz = (bid & 7) * 391 + (bid >> 3);
  const int mt = swz >> 2, nt = swz & 3;
  const int row0 = mt << 7, n0 = nt << 7;
  const int t = threadIdx.x;
  const int lane = t & 63, wv = t >> 6;
  const int wr = wv >> 1, wc = wv & 1;
  const int lr = lane & 15, lk = lane >> 4;

  __shared__ __align__(16) short As[128 * 32];
  __shared__ __align__(16) short Bs[128 * 32];

  const int srow0 = t >> 2, ck = t & 3;
  const short* ap1 = &Ab[(size_t)min(row0 + srow0, BATCH - 1) * KP + ck * 8];
  const short* ap2 = &Ab[(size_t)min(row0 + 64 + srow0, BATCH - 1) * KP + ck * 8];
  const short* bp1 = &WfT[(size_t)(n0 + srow0) * KP + ck * 8];
  const short* bp2 = &WfT[(size_t)(n0 + 64 + srow0) * KP + ck * 8];

  f32x4 acc[4][4];
#pragma unroll
  for (int i = 0; i < 4; ++i)
#pragma unroll
    for (int j = 0; j < 4; ++j) acc[i][j] = (f32x4){0.f, 0.f, 0.f, 0.f};

  for (int ks = 0; ks < 22; ++ks) {
    const int k0 = ks << 5;
    __syncthreads();
    glds16(ap1 + k0, &As[t * 8]);
    glds16(ap2 + k0, &As[2048 + t * 8]);
    glds16(bp1 + k0, &Bs[t * 8]);
    glds16(bp2 + k0, &Bs[2048 + t * 8]);
    __syncthreads();
    s16x8 af[4], bq[4];
#pragma unroll
    for (int mi = 0; mi < 4; ++mi)
      af[mi] = *(const s16x8*)&As[(wr * 64 + mi * 16 + lr) * 32 + lk * 8];
#pragma unroll
    for (int ni = 0; ni < 4; ++ni)
      bq[ni] = *(const s16x8*)&Bs[(wc * 64 + ni * 16 + lr) * 32 + lk * 8];
#pragma unroll
    for (int mi = 0; mi < 4; ++mi)
#pragma unroll
      for (int ni = 0; ni < 4; ++ni)
        acc[mi][ni] = __builtin_amdgcn_mfma_f32_16x16x32_bf16(af[mi], bq[ni], acc[mi][ni], 0, 0, 0);
  }

#pragma unroll
  for (int ni = 0; ni < 4; ++ni) {
    int col = n0 + wc * 64 + ni * 16 + lr;
    float bb = bfv[col];
#pragma unroll
    for (int mi = 0; mi < 4; ++mi) {
      int rbase = row0 + wr * 64 + mi * 16 + lk * 4;
#pragma unroll
      for (int rr = 0; rr < 4; ++rr) {
        int gr = rbase + rr;
        if (gr < BATCH) {
          float x = acc[mi][ni][rr] + bb;
          float y = x / (1.f + __expf(-x));
          out[(size_t)gr * 512 + col] = y;
          fob[(size_t)gr * 512 + col] = f2bf(y);
        }
      }
    }
  }
}

// ---------------------------------------------------------------------------
// K3: gating GEMM + sigmoid*Vub -> vectors_out f32.  M=100000, K=512, N=128.
// m97 structure: both operands bf16 via global_load_lds.
__global__ __launch_bounds__(256) void gemm_gate(
    const short* __restrict__ fob, const short* __restrict__ WgT,
    const float* __restrict__ bg, const short* __restrict__ Vub,
    float* __restrict__ out) {
  const int bid = blockIdx.x;
  const int xcd = bid & 7, bidx = bid >> 3;
  const int swz = (xcd < 6 ? xcd * 98 : 6 * 98 + (xcd - 6) * 97) + bidx;
  const int row0 = swz << 7;
  const int t = threadIdx.x;
  const int lane = t & 63, wv = t >> 6;
  const int wr = wv >> 1, wc = wv & 1;
  const int lr = lane & 15, lk = lane >> 4;

  __shared__ __align__(16) short As[128 * 32];
  __shared__ __align__(16) short Bs[128 * 32];

  const int srow0 = t >> 2, ck = t & 3;
  const short* ap1 = &fob[(size_t)min(row0 + srow0, BATCH - 1) * 512 + ck * 8];
  const short* ap2 = &fob[(size_t)min(row0 + 64 + srow0, BATCH - 1) * 512 + ck * 8];
  const short* bp1 = &WgT[(size_t)srow0 * 512 + ck * 8];
  const short* bp2 = &WgT[(size_t)(64 + srow0) * 512 + ck * 8];

  f32x4 acc[4][4];
#pragma unroll
  for (int i = 0; i < 4; ++i)
#pragma unroll
    for (int j = 0; j < 4; ++j) acc[i][j] = (f32x4){0.f, 0.f, 0.f, 0.f};

  for (int ks = 0; ks < 16; ++ks) {
    const int k0 = ks << 5;
    __syncthreads();
    glds16(ap1 + k0, &As[t * 8]);
    glds16(ap2 + k0, &As[2048 + t * 8]);
    glds16(bp1 + k0, &Bs[t * 8]);
    glds16(bp2 + k0, &Bs[2048 + t * 8]);
    __syncthreads();
    s16x8 af[4], bq[4];
#pragma unroll
    for (int mi = 0; mi < 4; ++mi)
      af[mi] = *(const s16x8*)&As[(wr * 64 + mi * 16 + lr) * 32 + lk * 8];
#pragma unroll
    for (int ni = 0; ni < 4; ++ni)
      bq[ni] = *(const s16x8*)&Bs[(wc * 64 + ni * 16 + lr) * 32 + lk * 8];
#pragma unroll
    for (int mi = 0; mi < 4; ++mi)
#pragma unroll
      for (int ni = 0; ni < 4; ++ni)
        acc[mi][ni] = __builtin_amdgcn_mfma_f32_16x16x32_bf16(af[mi], bq[ni], acc[mi][ni], 0, 0, 0);
  }

#pragma unroll
  for (int ni = 0; ni < 4; ++ni) {
    int col = wc * 64 + ni * 16 + lr;
    float bb = bg[col];
#pragma unroll
    for (int mi = 0; mi < 4; ++mi) {
      int rbase = row0 + wr * 64 + mi * 16 + lk * 4;
#pragma unroll
      for (int rr = 0; rr < 4; ++rr) {
        int gr = rbase + rr;
        if (gr < BATCH) {
          float x = acc[mi][ni][rr] + bb;
          float gate = 1.f / (1.f + __expf(-x));
          size_t vb = (size_t)(3 * gr) * 128 + col;
          float* po = &out[VECBASE + ((size_t)gr * 128 + col) * 3];
          po[0] = gate * bf2f(Vub[vb]);
          po[1] = gate * bf2f(Vub[vb + 128]);
          po[2] = gate * bf2f(Vub[vb + 256]);
        }
      }
    }
  }
}

// ---------------------------------------------------------------------------
extern "C" void kernel_launch(void* const* d_in, const int* in_sizes, int n_in,
                              void* d_out, int out_size, void* d_ws, size_t ws_size,
                              hipStream_t stream) {
  const float* feats = (const float*)d_in[0];
  const float* vecs  = (const float*)d_in[1];
  const float* Wh    = (const float*)d_in[2];
  const float* Wcp   = (const float*)d_in[3];
  const float* Wu    = (const float*)d_in[4];
  const float* Wf    = (const float*)d_in[5];
  const float* bfv   = (const float*)d_in[6];
  const float* Wg    = (const float*)d_in[7];
  const float* bg    = (const float*)d_in[8];
  float* out = (float*)d_out;

  char* ws = (char*)d_ws;
  short* Ab   = (short*)ws;                                // 100000*704*2 = 140,800,000
  short* Vub  = (short*)(ws + 140800000);                  // 300000*128*2 =  76,800,000
  short* fob  = (short*)(ws + 217600000);                  // 100000*512*2 = 102,400,000
  short* WfT  = (short*)(ws + 320000000);                  // 512*704*2    =     720,896
  short* WgT  = (short*)(ws + 320720896);                  // 128*512*2    =     131,072
  short* WB1  = (short*)(ws + 320851968);                  //                     40,960
  short* WuTp = (short*)(ws + 320892928);                  //                     40,960

  hipLaunchKernelGGL(prep_w,     dim3(2048), dim3(256), 0, stream,
                     feats, Wh, Wcp, Wu, Wf, Wg, Ab, WB1, WuTp, WfT, WgT);
  hipLaunchKernelGGL(geo_fused,  dim3(1563), dim3(256), 0, stream,
                     vecs, WB1, WuTp, Ab, Vub);
  hipLaunchKernelGGL(gemm_feats, dim3(3128), dim3(256), 0, stream,
                     Ab, WfT, bfv, out, fob);
  hipLaunchKernelGGL(gemm_gate,  dim3(782),  dim3(256), 0, stream,
                     fob, WgT, bg, Vub, out);
}

// Round 8
// 529.527 us; speedup vs baseline: 1.0294x; 1.0049x over previous
//
#include <hip/hip_runtime.h>

#define BATCH 100000
#define M3 300000            // 3*BATCH rows
#define VECBASE 51200000     // BATCH*512 floats; start of vectors_out region in d_out
#define KP 704               // padded K for Ab/WfT (656 -> 11*64)

typedef float fl4  __attribute__((ext_vector_type(4)));
typedef float f32x4 __attribute__((ext_vector_type(4)));
typedef short s16x4 __attribute__((ext_vector_type(4)));
typedef short s16x8 __attribute__((ext_vector_type(8)));

__device__ __forceinline__ short f2bf(float f) {
  unsigned int u = __float_as_uint(f);
  u += 0x7fffu + ((u >> 16) & 1u);
  return (short)(u >> 16);
}
__device__ __forceinline__ float bf2f(short s) {
  return __uint_as_float(((unsigned int)(unsigned short)s) << 16);
}
__device__ __forceinline__ s16x8 pack8(fl4 a, fl4 b) {
  s16x8 o;
  o[0] = f2bf(a[0]); o[1] = f2bf(a[1]); o[2] = f2bf(a[2]); o[3] = f2bf(a[3]);
  o[4] = f2bf(b[0]); o[5] = f2bf(b[1]); o[6] = f2bf(b[2]); o[7] = f2bf(b[3]);
  return o;
}
__device__ __forceinline__ void glds16(const void* g, void* l) {
  __builtin_amdgcn_global_load_lds((const __attribute__((address_space(1))) void*)g,
                                   (__attribute__((address_space(3))) void*)l, 16, 0, 0);
}

// ---------------------------------------------------------------------------
// K0: prep. (a) feats -> Ab[:,0:512) bf16 (streaming); (b) weight transposes.
__global__ __launch_bounds__(256) void prep_w(
    const float* __restrict__ feats, const float* __restrict__ Wh,
    const float* __restrict__ Wcp, const float* __restrict__ Wu,
    const float* __restrict__ Wf, const float* __restrict__ Wg,
    short* __restrict__ Ab, short* __restrict__ WB1, short* __restrict__ WuTp,
    short* __restrict__ WfT, short* __restrict__ WgT) {
  const int tid = blockIdx.x * 256 + threadIdx.x;
  const int stride = gridDim.x * 256;
  for (int i = tid; i < 6400000; i += stride) {
    int b = i >> 6, kk = (i & 63) * 8;
    fl4 v0 = *reinterpret_cast<const fl4*>(&feats[(size_t)b * 512 + kk]);
    fl4 v1 = *reinterpret_cast<const fl4*>(&feats[(size_t)b * 512 + kk + 4]);
    *(s16x8*)&Ab[(size_t)b * KP + kk] = pack8(v0, v1);
  }
  for (int gid = tid; gid < 466944; gid += stride) {
    if (gid < 20480) {                       // WB1 [160][128]
      int n = gid >> 7, k = gid & 127;
      WB1[gid] = f2bf(n < 128 ? Wh[k * 128 + n] : Wcp[k * 32 + (n - 128)]);
    } else if (gid < 40960) {                // WuTp [128][160]
      int i = gid - 20480;
      int o = i / 160, k = i - o * 160;
      WuTp[i] = k < 144 ? f2bf(Wu[k * 128 + o]) : (short)0;
    } else if (gid < 401408) {               // WfT [512][704]
      int i = gid - 40960;
      int n = i / KP, k = i - n * KP;
      WfT[i] = k < 656 ? f2bf(Wf[k * 512 + n]) : (short)0;
    } else {                                 // WgT [128][512]
      int i = gid - 401408;
      int n = i >> 9, k = i & 511;
      WgT[i] = f2bf(Wg[k * 128 + n]);
    }
  }
}

// ---------------------------------------------------------------------------
// K1: geo_fused. Per block (64 b's = 192 rows):
//   GEMM1 D[192][160] = A[192][128] @ WB1^T; cross -> cols 128..143;
//   norms -> Ab cols 512..655 (+zeros); GEMM2 -> Vub bf16.
__global__ __launch_bounds__(256) void geo_fused(
    const float* __restrict__ vecs, const short* __restrict__ WB1,
    const short* __restrict__ WuTp, short* __restrict__ Ab,
    short* __restrict__ Vub) {
  __shared__ __align__(16) short U[192 * 168];   // 64,512 B
  const int t = threadIdx.x;
  const int b0 = blockIdx.x * 64;
  const int row0 = blockIdx.x * 192;

  // stage A [192][128] bf16 (pitch 256B, XOR swizzle): 12-float spans, 3x ds_write_b64
#pragma unroll
  for (int it = 0; it < 8; ++it) {
    int fi = (it * 256 + t) * 12;
    int bl = fi / 384;
    int rem = fi - bl * 384;           // multiple of 12
    int v0 = rem / 3;                  // multiple of 4
    int b = b0 + bl;
    fl4 x = (fl4){0.f, 0.f, 0.f, 0.f}, y = x, z = x;
    if (b < BATCH) {
      const float* p = &vecs[(size_t)b * 384 + rem];
      x = *(const fl4*)p; y = *(const fl4*)(p + 4); z = *(const fl4*)(p + 8);
    }
    float vc[3][4] = {{x[0], x[3], y[2], z[1]},
                      {x[1], y[0], y[3], z[2]},
                      {x[2], y[1], z[0], z[3]}};
#pragma unroll
    for (int c = 0; c < 3; ++c) {
      int row = bl * 3 + c;
      s16x4 q;
#pragma unroll
      for (int e = 0; e < 4; ++e) q[e] = f2bf(vc[c][e]);
      int off = (row << 8) + (v0 << 1);
      *(s16x4*)((char*)U + (off ^ ((row & 7) << 4))) = q;
    }
  }
  __syncthreads();

  const int lane = t & 63, wv = t >> 6;
  const int wr = wv >> 1, wc = wv & 1;
  const int lr = lane & 15, lk = lane >> 4;

  {  // GEMM1
    f32x4 acc[6][5];
#pragma unroll
    for (int i = 0; i < 6; ++i)
#pragma unroll
      for (int j = 0; j < 5; ++j) acc[i][j] = (f32x4){0.f, 0.f, 0.f, 0.f};
#pragma unroll
    for (int kk = 0; kk < 4; ++kk) {
      s16x8 af[6], bq[5];
#pragma unroll
      for (int mi = 0; mi < 6; ++mi) {
        int row = wr * 96 + mi * 16 + lr;
        int off = (row << 8) + (kk << 6) + (lk << 4);
        af[mi] = *(const s16x8*)((const char*)U + (off ^ ((row & 7) << 4)));
      }
#pragma unroll
      for (int ni = 0; ni < 5; ++ni)
        bq[ni] = *reinterpret_cast<const s16x8*>(
            &WB1[(wc * 80 + ni * 16 + lr) * 128 + (kk << 5) + (lk << 3)]);
      __builtin_amdgcn_s_setprio(1);
#pragma unroll
      for (int mi = 0; mi < 6; ++mi)
#pragma unroll
        for (int ni = 0; ni < 5; ++ni)
          acc[mi][ni] = __builtin_amdgcn_mfma_f32_16x16x32_bf16(af[mi], bq[ni], acc[mi][ni], 0, 0, 0);
      __builtin_amdgcn_s_setprio(0);
    }
    __syncthreads();
#pragma unroll
    for (int mi = 0; mi < 6; ++mi)
#pragma unroll
      for (int ni = 0; ni < 5; ++ni) {
        int col = wc * 80 + ni * 16 + lr;
#pragma unroll
        for (int r = 0; r < 4; ++r) {
          int row = wr * 96 + mi * 16 + lk * 4 + r;
          U[row * 168 + col] = f2bf(acc[mi][ni][r]);
        }
      }
  }
  __syncthreads();

  {  // cross
    int bl = t >> 2, pj = t & 3;
    int gb = b0 + bl;
    float shcp[4];
#pragma unroll
    for (int q = 0; q < 4; ++q) {
      int p = pj * 4 + q;
      float ax = bf2f(U[(bl * 3 + 0) * 168 + 128 + p]);
      float ay = bf2f(U[(bl * 3 + 1) * 168 + 128 + p]);
      float az = bf2f(U[(bl * 3 + 2) * 168 + 128 + p]);
      float bx = bf2f(U[(bl * 3 + 0) * 168 + 144 + p]);
      float by = bf2f(U[(bl * 3 + 1) * 168 + 144 + p]);
      float bz = bf2f(U[(bl * 3 + 2) * 168 + 144 + p]);
      float cx = ay * bz - az * by;
      float cy = az * bx - ax * bz;
      float cz = ax * by - ay * bx;
      U[(bl * 3 + 0) * 168 + 128 + p] = f2bf(cx);
      U[(bl * 3 + 1) * 168 + 128 + p] = f2bf(cy);
      U[(bl * 3 + 2) * 168 + 128 + p] = f2bf(cz);
      U[(bl * 3 + 0) * 168 + 144 + p] = 0;
      U[(bl * 3 + 1) * 168 + 144 + p] = 0;
      U[(bl * 3 + 2) * 168 + 144 + p] = 0;
      shcp[q] = sqrtf(fmaxf(cx * cx + cy * cy + cz * cz, 1e-8f));
    }
    if (gb < BATCH) {
#pragma unroll
      for (int q = 0; q < 4; ++q)
        Ab[(size_t)gb * KP + 512 + 128 + pj * 4 + q] = f2bf(shcp[q]);
#pragma unroll
      for (int z = 0; z < 12; ++z)
        Ab[(size_t)gb * KP + 512 + 144 + pj * 12 + z] = 0;
    }
  }
  {  // norms k<128 (disjoint cols; no barrier needed)
    int bl = t >> 2, kq = t & 3;
    int gb = b0 + bl;
    if (gb < BATCH) {
#pragma unroll
      for (int j = 0; j < 4; ++j) {
        int k = kq * 32 + j * 8;
        s16x8 r0 = *(const s16x8*)&U[(bl * 3 + 0) * 168 + k];
        s16x8 r1 = *(const s16x8*)&U[(bl * 3 + 1) * 168 + k];
        s16x8 r2 = *(const s16x8*)&U[(bl * 3 + 2) * 168 + k];
        s16x8 o;
#pragma unroll
        for (int e = 0; e < 8; ++e) {
          float x = bf2f(r0[e]), y = bf2f(r1[e]), z = bf2f(r2[e]);
          o[e] = f2bf(sqrtf(fmaxf(x * x + y * y + z * z, 1e-8f)));
        }
        *(s16x8*)&Ab[(size_t)gb * KP + 512 + k] = o;
      }
    }
  }
  __syncthreads();

  {  // GEMM2: Vu[192][128] = U[192][160] @ WuTp^T
    f32x4 acc2[6][4];
#pragma unroll
    for (int i = 0; i < 6; ++i)
#pragma unroll
      for (int j = 0; j < 4; ++j) acc2[i][j] = (f32x4){0.f, 0.f, 0.f, 0.f};
#pragma unroll
    for (int kk = 0; kk < 5; ++kk) {
      s16x8 af[6], bq[4];
#pragma unroll
      for (int mi = 0; mi < 6; ++mi) {
        int row = wr * 96 + mi * 16 + lr;
        af[mi] = *(const s16x8*)&U[row * 168 + (kk << 5) + (lk << 3)];
      }
#pragma unroll
      for (int ni = 0; ni < 4; ++ni)
        bq[ni] = *reinterpret_cast<const s16x8*>(
            &WuTp[(wc * 64 + ni * 16 + lr) * 160 + (kk << 5) + (lk << 3)]);
      __builtin_amdgcn_s_setprio(1);
#pragma unroll
      for (int mi = 0; mi < 6; ++mi)
#pragma unroll
        for (int ni = 0; ni < 4; ++ni)
          acc2[mi][ni] = __builtin_amdgcn_mfma_f32_16x16x32_bf16(af[mi], bq[ni], acc2[mi][ni], 0, 0, 0);
      __builtin_amdgcn_s_setprio(0);
    }
#pragma unroll
    for (int mi = 0; mi < 6; ++mi)
#pragma unroll
      for (int ni = 0; ni < 4; ++ni) {
        int col = wc * 64 + ni * 16 + lr;
#pragma unroll
        for (int r = 0; r < 4; ++r) {
          int row = row0 + wr * 96 + mi * 16 + lk * 4 + r;
          if (row < M3) Vub[(size_t)row * 128 + col] = f2bf(acc2[mi][ni][r]);
        }
      }
  }
}

// ---------------------------------------------------------------------------
// K2: feats_out = silu(Ab @ Wf + bf) -> out f32 + fob bf16.
// 2-phase double-buffered glds pipeline, BK=64, source-permuted chunk swizzle.
__global__ __launch_bounds__(256) void gemm_feats(
    const short* __restrict__ Ab, const short* __restrict__ WfT,
    const float* __restrict__ bfv, float* __restrict__ out,
    short* __restrict__ fob) {
  const int bid = blockIdx.x;
  const int swz = (bid & 7) * 391 + (bid >> 3);
  const int mt = swz >> 2, nt = swz & 3;
  const int row0 = mt << 7, n0 = nt << 7;
  const int t = threadIdx.x;
  const int lane = t & 63, wv = t >> 6;
  const int wr = wv >> 1, wc = wv & 1;
  const int lr = lane & 15, lk = lane >> 4;

  __shared__ __align__(16) short As[2][128 * 64];   // 32 KB
  __shared__ __align__(16) short Bs[2][128 * 64];   // 32 KB

  // staging: 4 A-chunks + 4 B-chunks per thread; LDS dest linear (cid*16B),
  // global source chunk permuted: ch_src = ch ^ (row&7)  [rule #21]
  const short* srcA[4];
  const short* srcB[4];
  int dofs[4];
#pragma unroll
  for (int j = 0; j < 4; ++j) {
    int cid = j * 256 + t;
    int row = cid >> 3, ch = cid & 7;
    int chs = ch ^ (row & 7);
    srcA[j] = &Ab[(size_t)min(row0 + row, BATCH - 1) * KP + chs * 8];
    srcB[j] = &WfT[(size_t)(n0 + row) * KP + chs * 8];
    dofs[j] = cid * 8;
  }

  f32x4 acc[4][4];
#pragma unroll
  for (int i = 0; i < 4; ++i)
#pragma unroll
    for (int j = 0; j < 4; ++j) acc[i][j] = (f32x4){0.f, 0.f, 0.f, 0.f};

  auto STAGE = [&](int buf, int ks) {
    const int k0 = ks << 6;
#pragma unroll
    for (int j = 0; j < 4; ++j) glds16(srcA[j] + k0, &As[buf][dofs[j]]);
#pragma unroll
    for (int j = 0; j < 4; ++j) glds16(srcB[j] + k0, &Bs[buf][dofs[j]]);
  };
  auto COMPUTE = [&](int buf) {
#pragma unroll
    for (int kk = 0; kk < 2; ++kk) {
      s16x8 af[4], bq[4];
#pragma unroll
      for (int mi = 0; mi < 4; ++mi) {
        int rw = wr * 64 + mi * 16 + lr;
        af[mi] = *(const s16x8*)&As[buf][rw * 64 + (((kk << 2) + lk) ^ (rw & 7)) * 8];
      }
#pragma unroll
      for (int ni = 0; ni < 4; ++ni) {
        int rw = wc * 64 + ni * 16 + lr;
        bq[ni] = *(const s16x8*)&Bs[buf][rw * 64 + (((kk << 2) + lk) ^ (rw & 7)) * 8];
      }
      __builtin_amdgcn_s_setprio(1);
#pragma unroll
      for (int mi = 0; mi < 4; ++mi)
#pragma unroll
        for (int ni = 0; ni < 4; ++ni)
          acc[mi][ni] = __builtin_amdgcn_mfma_f32_16x16x32_bf16(af[mi], bq[ni], acc[mi][ni], 0, 0, 0);
      __builtin_amdgcn_s_setprio(0);
    }
  };

  STAGE(0, 0);
  __syncthreads();
  for (int ks = 0; ks < 11; ++ks) {
    if (ks + 1 < 11) STAGE((ks + 1) & 1, ks + 1);
    COMPUTE(ks & 1);
    __syncthreads();
  }

#pragma unroll
  for (int ni = 0; ni < 4; ++ni) {
    int col = n0 + wc * 64 + ni * 16 + lr;
    float bb = bfv[col];
#pragma unroll
    for (int mi = 0; mi < 4; ++mi) {
      int rbase = row0 + wr * 64 + mi * 16 + lk * 4;
#pragma unroll
      for (int rr = 0; rr < 4; ++rr) {
        int gr = rbase + rr;
        if (gr < BATCH) {
          float x = acc[mi][ni][rr] + bb;
          float y = x / (1.f + __expf(-x));
          out[(size_t)gr * 512 + col] = y;
          fob[(size_t)gr * 512 + col] = f2bf(y);
        }
      }
    }
  }
}

// ---------------------------------------------------------------------------
// K3: gating GEMM + sigmoid*Vub -> vectors_out f32.  Same 2-phase structure.
__global__ __launch_bounds__(256) void gemm_gate(
    const short* __restrict__ fob, const short* __restrict__ WgT,
    const float* __restrict__ bg, const short* __restrict__ Vub,
    float* __restrict__ out) {
  const int bid = blockIdx.x;
  const int xcd = bid & 7, bidx = bid >> 3;
  const int swz = (xcd < 6 ? xcd * 98 : 6 * 98 + (xcd - 6) * 97) + bidx;
  const int row0 = swz << 7;
  const int t = threadIdx.x;
  const int lane = t & 63, wv = t >> 6;
  const int wr = wv >> 1, wc = wv & 1;
  const int lr = lane & 15, lk = lane >> 4;

  __shared__ __align__(16) short As[2][128 * 64];
  __shared__ __align__(16) short Bs[2][128 * 64];

  const short* srcA[4];
  const short* srcB[4];
  int dofs[4];
#pragma unroll
  for (int j = 0; j < 4; ++j) {
    int cid = j * 256 + t;
    int row = cid >> 3, ch = cid & 7;
    int chs = ch ^ (row & 7);
    srcA[j] = &fob[(size_t)min(row0 + row, BATCH - 1) * 512 + chs * 8];
    srcB[j] = &WgT[(size_t)row * 512 + chs * 8];
    dofs[j] = cid * 8;
  }

  f32x4 acc[4][4];
#pragma unroll
  for (int i = 0; i < 4; ++i)
#pragma unroll
    for (int j = 0; j < 4; ++j) acc[i][j] = (f32x4){0.f, 0.f, 0.f, 0.f};

  auto STAGE = [&](int buf, int ks) {
    const int k0 = ks << 6;
#pragma unroll
    for (int j = 0; j < 4; ++j) glds16(srcA[j] + k0, &As[buf][dofs[j]]);
#pragma unroll
    for (int j = 0; j < 4; ++j) glds16(srcB[j] + k0, &Bs[buf][dofs[j]]);
  };
  auto COMPUTE = [&](int buf) {
#pragma unroll
    for (int kk = 0; kk < 2; ++kk) {
      s16x8 af[4], bq[4];
#pragma unroll
      for (int mi = 0; mi < 4; ++mi) {
        int rw = wr * 64 + mi * 16 + lr;
        af[mi] = *(const s16x8*)&As[buf][rw * 64 + (((kk << 2) + lk) ^ (rw & 7)) * 8];
      }
#pragma unroll
      for (int ni = 0; ni < 4; ++ni) {
        int rw = wc * 64 + ni * 16 + lr;
        bq[ni] = *(const s16x8*)&Bs[buf][rw * 64 + (((kk << 2) + lk) ^ (rw & 7)) * 8];
      }
      __builtin_amdgcn_s_setprio(1);
#pragma unroll
      for (int mi = 0; mi < 4; ++mi)
#pragma unroll
        for (int ni = 0; ni < 4; ++ni)
          acc[mi][ni] = __builtin_amdgcn_mfma_f32_16x16x32_bf16(af[mi], bq[ni], acc[mi][ni], 0, 0, 0);
      __builtin_amdgcn_s_setprio(0);
    }
  };

  STAGE(0, 0);
  __syncthreads();
  for (int ks = 0; ks < 8; ++ks) {
    if (ks + 1 < 8) STAGE((ks + 1) & 1, ks + 1);
    COMPUTE(ks & 1);
    __syncthreads();
  }

#pragma unroll
  for (int ni = 0; ni < 4; ++ni) {
    int col = wc * 64 + ni * 16 + lr;
    float bb = bg[col];
#pragma unroll
    for (int mi = 0; mi < 4; ++mi) {
      int rbase = row0 + wr * 64 + mi * 16 + lk * 4;
#pragma unroll
      for (int rr = 0; rr < 4; ++rr) {
        int gr = rbase + rr;
        if (gr < BATCH) {
          float x = acc[mi][ni][rr] + bb;
          float gate = 1.f / (1.f + __expf(-x));
          size_t vb = (size_t)(3 * gr) * 128 + col;
          float* po = &out[VECBASE + ((size_t)gr * 128 + col) * 3];
          po[0] = gate * bf2f(Vub[vb]);
          po[1] = gate * bf2f(Vub[vb + 128]);
          po[2] = gate * bf2f(Vub[vb + 256]);
        }
      }
    }
  }
}

// ---------------------------------------------------------------------------
extern "C" void kernel_launch(void* const* d_in, const int* in_sizes, int n_in,
                              void* d_out, int out_size, void* d_ws, size_t ws_size,
                              hipStream_t stream) {
  const float* feats = (const float*)d_in[0];
  const float* vecs  = (const float*)d_in[1];
  const float* Wh    = (const float*)d_in[2];
  const float* Wcp   = (const float*)d_in[3];
  const float* Wu    = (const float*)d_in[4];
  const float* Wf    = (const float*)d_in[5];
  const float* bfv   = (const float*)d_in[6];
  const float* Wg    = (const float*)d_in[7];
  const float* bg    = (const float*)d_in[8];
  float* out = (float*)d_out;

  char* ws = (char*)d_ws;
  short* Ab   = (short*)ws;                                // 140,800,000 B
  short* Vub  = (short*)(ws + 140800000);                  //  76,800,000 B
  short* fob  = (short*)(ws + 217600000);                  // 102,400,000 B
  short* WfT  = (short*)(ws + 320000000);                  //     720,896 B
  short* WgT  = (short*)(ws + 320720896);                  //     131,072 B
  short* WB1  = (short*)(ws + 320851968);                  //      40,960 B
  short* WuTp = (short*)(ws + 320892928);                  //      40,960 B

  hipLaunchKernelGGL(prep_w,     dim3(2048), dim3(256), 0, stream,
                     feats, Wh, Wcp, Wu, Wf, Wg, Ab, WB1, WuTp, WfT, WgT);
  hipLaunchKernelGGL(geo_fused,  dim3(1563), dim3(256), 0, stream,
                     vecs, WB1, WuTp, Ab, Vub);
  hipLaunchKernelGGL(gemm_feats, dim3(3128), dim3(256), 0, stream,
                     Ab, WfT, bfv, out, fob);
  hipLaunchKernelGGL(gemm_gate,  dim3(782),  dim3(256), 0, stream,
                     fob, WgT, bg, Vub, out);
}

// Round 9
// 513.937 us; speedup vs baseline: 1.0606x; 1.0303x over previous
//
#include <hip/hip_runtime.h>

#define BATCH 100000
#define M3 300000            // 3*BATCH rows
#define VECBASE 51200000     // BATCH*512 floats; start of vectors_out region in d_out
#define KP 704               // padded K for Ab/WfT (656 -> 22*32)

typedef float fl4  __attribute__((ext_vector_type(4)));
typedef float f32x4 __attribute__((ext_vector_type(4)));
typedef short s16x4 __attribute__((ext_vector_type(4)));
typedef short s16x8 __attribute__((ext_vector_type(8)));

__device__ __forceinline__ short f2bf(float f) {
  unsigned int u = __float_as_uint(f);
  u += 0x7fffu + ((u >> 16) & 1u);
  return (short)(u >> 16);
}
__device__ __forceinline__ float bf2f(short s) {
  return __uint_as_float(((unsigned int)(unsigned short)s) << 16);
}
__device__ __forceinline__ s16x8 pack8(fl4 a, fl4 b) {
  s16x8 o;
  o[0] = f2bf(a[0]); o[1] = f2bf(a[1]); o[2] = f2bf(a[2]); o[3] = f2bf(a[3]);
  o[4] = f2bf(b[0]); o[5] = f2bf(b[1]); o[6] = f2bf(b[2]); o[7] = f2bf(b[3]);
  return o;
}
__device__ __forceinline__ void glds16(const void* g, void* l) {
  __builtin_amdgcn_global_load_lds((const __attribute__((address_space(1))) void*)g,
                                   (__attribute__((address_space(3))) void*)l, 16, 0, 0);
}
// counted-vmcnt barrier: wait then barrier in ONE asm so nothing slides between
#define WAITBAR(N) asm volatile("s_waitcnt vmcnt(" #N ")\ns_barrier" ::: "memory")
#define RAWBAR()   asm volatile("s_barrier" ::: "memory")

// ---------------------------------------------------------------------------
// K0: prep. (a) feats -> Ab[:,0:512) bf16 (streaming); (b) weight transposes.
__global__ __launch_bounds__(256) void prep_w(
    const float* __restrict__ feats, const float* __restrict__ Wh,
    const float* __restrict__ Wcp, const float* __restrict__ Wu,
    const float* __restrict__ Wf, const float* __restrict__ Wg,
    short* __restrict__ Ab, short* __restrict__ WB1, short* __restrict__ WuTp,
    short* __restrict__ WfT, short* __restrict__ WgT) {
  const int tid = blockIdx.x * 256 + threadIdx.x;
  const int stride = gridDim.x * 256;
  for (int i = tid; i < 6400000; i += stride) {
    int b = i >> 6, kk = (i & 63) * 8;
    fl4 v0 = *reinterpret_cast<const fl4*>(&feats[(size_t)b * 512 + kk]);
    fl4 v1 = *reinterpret_cast<const fl4*>(&feats[(size_t)b * 512 + kk + 4]);
    *(s16x8*)&Ab[(size_t)b * KP + kk] = pack8(v0, v1);
  }
  for (int gid = tid; gid < 466944; gid += stride) {
    if (gid < 20480) {                       // WB1 [160][128]
      int n = gid >> 7, k = gid & 127;
      WB1[gid] = f2bf(n < 128 ? Wh[k * 128 + n] : Wcp[k * 32 + (n - 128)]);
    } else if (gid < 40960) {                // WuTp [128][160]
      int i = gid - 20480;
      int o = i / 160, k = i - o * 160;
      WuTp[i] = k < 144 ? f2bf(Wu[k * 128 + o]) : (short)0;
    } else if (gid < 401408) {               // WfT [512][704]
      int i = gid - 40960;
      int n = i / KP, k = i - n * KP;
      WfT[i] = k < 656 ? f2bf(Wf[k * 512 + n]) : (short)0;
    } else {                                 // WgT [128][512]
      int i = gid - 401408;
      int n = i >> 9, k = i & 511;
      WgT[i] = f2bf(Wg[k * 128 + n]);
    }
  }
}

// ---------------------------------------------------------------------------
// K1: geo_fused (unchanged from R8): GEMM1 + cross + norms->Ab + GEMM2->Vub.
__global__ __launch_bounds__(256) void geo_fused(
    const float* __restrict__ vecs, const short* __restrict__ WB1,
    const short* __restrict__ WuTp, short* __restrict__ Ab,
    short* __restrict__ Vub) {
  __shared__ __align__(16) short U[192 * 168];
  const int t = threadIdx.x;
  const int b0 = blockIdx.x * 64;
  const int row0 = blockIdx.x * 192;

#pragma unroll
  for (int it = 0; it < 8; ++it) {
    int fi = (it * 256 + t) * 12;
    int bl = fi / 384;
    int rem = fi - bl * 384;
    int v0 = rem / 3;
    int b = b0 + bl;
    fl4 x = (fl4){0.f, 0.f, 0.f, 0.f}, y = x, z = x;
    if (b < BATCH) {
      const float* p = &vecs[(size_t)b * 384 + rem];
      x = *(const fl4*)p; y = *(const fl4*)(p + 4); z = *(const fl4*)(p + 8);
    }
    float vc[3][4] = {{x[0], x[3], y[2], z[1]},
                      {x[1], y[0], y[3], z[2]},
                      {x[2], y[1], z[0], z[3]}};
#pragma unroll
    for (int c = 0; c < 3; ++c) {
      int row = bl * 3 + c;
      s16x4 q;
#pragma unroll
      for (int e = 0; e < 4; ++e) q[e] = f2bf(vc[c][e]);
      int off = (row << 8) + (v0 << 1);
      *(s16x4*)((char*)U + (off ^ ((row & 7) << 4))) = q;
    }
  }
  __syncthreads();

  const int lane = t & 63, wv = t >> 6;
  const int wr = wv >> 1, wc = wv & 1;
  const int lr = lane & 15, lk = lane >> 4;

  {  // GEMM1
    f32x4 acc[6][5];
#pragma unroll
    for (int i = 0; i < 6; ++i)
#pragma unroll
      for (int j = 0; j < 5; ++j) acc[i][j] = (f32x4){0.f, 0.f, 0.f, 0.f};
#pragma unroll
    for (int kk = 0; kk < 4; ++kk) {
      s16x8 af[6], bq[5];
#pragma unroll
      for (int mi = 0; mi < 6; ++mi) {
        int row = wr * 96 + mi * 16 + lr;
        int off = (row << 8) + (kk << 6) + (lk << 4);
        af[mi] = *(const s16x8*)((const char*)U + (off ^ ((row & 7) << 4)));
      }
#pragma unroll
      for (int ni = 0; ni < 5; ++ni)
        bq[ni] = *reinterpret_cast<const s16x8*>(
            &WB1[(wc * 80 + ni * 16 + lr) * 128 + (kk << 5) + (lk << 3)]);
      __builtin_amdgcn_s_setprio(1);
#pragma unroll
      for (int mi = 0; mi < 6; ++mi)
#pragma unroll
        for (int ni = 0; ni < 5; ++ni)
          acc[mi][ni] = __builtin_amdgcn_mfma_f32_16x16x32_bf16(af[mi], bq[ni], acc[mi][ni], 0, 0, 0);
      __builtin_amdgcn_s_setprio(0);
    }
    __syncthreads();
#pragma unroll
    for (int mi = 0; mi < 6; ++mi)
#pragma unroll
      for (int ni = 0; ni < 5; ++ni) {
        int col = wc * 80 + ni * 16 + lr;
#pragma unroll
        for (int r = 0; r < 4; ++r) {
          int row = wr * 96 + mi * 16 + lk * 4 + r;
          U[row * 168 + col] = f2bf(acc[mi][ni][r]);
        }
      }
  }
  __syncthreads();

  {  // cross
    int bl = t >> 2, pj = t & 3;
    int gb = b0 + bl;
    float shcp[4];
#pragma unroll
    for (int q = 0; q < 4; ++q) {
      int p = pj * 4 + q;
      float ax = bf2f(U[(bl * 3 + 0) * 168 + 128 + p]);
      float ay = bf2f(U[(bl * 3 + 1) * 168 + 128 + p]);
      float az = bf2f(U[(bl * 3 + 2) * 168 + 128 + p]);
      float bx = bf2f(U[(bl * 3 + 0) * 168 + 144 + p]);
      float by = bf2f(U[(bl * 3 + 1) * 168 + 144 + p]);
      float bz = bf2f(U[(bl * 3 + 2) * 168 + 144 + p]);
      float cx = ay * bz - az * by;
      float cy = az * bx - ax * bz;
      float cz = ax * by - ay * bx;
      U[(bl * 3 + 0) * 168 + 128 + p] = f2bf(cx);
      U[(bl * 3 + 1) * 168 + 128 + p] = f2bf(cy);
      U[(bl * 3 + 2) * 168 + 128 + p] = f2bf(cz);
      U[(bl * 3 + 0) * 168 + 144 + p] = 0;
      U[(bl * 3 + 1) * 168 + 144 + p] = 0;
      U[(bl * 3 + 2) * 168 + 144 + p] = 0;
      shcp[q] = sqrtf(fmaxf(cx * cx + cy * cy + cz * cz, 1e-8f));
    }
    if (gb < BATCH) {
#pragma unroll
      for (int q = 0; q < 4; ++q)
        Ab[(size_t)gb * KP + 512 + 128 + pj * 4 + q] = f2bf(shcp[q]);
#pragma unroll
      for (int z = 0; z < 12; ++z)
        Ab[(size_t)gb * KP + 512 + 144 + pj * 12 + z] = 0;
    }
  }
  {  // norms k<128
    int bl = t >> 2, kq = t & 3;
    int gb = b0 + bl;
    if (gb < BATCH) {
#pragma unroll
      for (int j = 0; j < 4; ++j) {
        int k = kq * 32 + j * 8;
        s16x8 r0 = *(const s16x8*)&U[(bl * 3 + 0) * 168 + k];
        s16x8 r1 = *(const s16x8*)&U[(bl * 3 + 1) * 168 + k];
        s16x8 r2 = *(const s16x8*)&U[(bl * 3 + 2) * 168 + k];
        s16x8 o;
#pragma unroll
        for (int e = 0; e < 8; ++e) {
          float x = bf2f(r0[e]), y = bf2f(r1[e]), z = bf2f(r2[e]);
          o[e] = f2bf(sqrtf(fmaxf(x * x + y * y + z * z, 1e-8f)));
        }
        *(s16x8*)&Ab[(size_t)gb * KP + 512 + k] = o;
      }
    }
  }
  __syncthreads();

  {  // GEMM2
    f32x4 acc2[6][4];
#pragma unroll
    for (int i = 0; i < 6; ++i)
#pragma unroll
      for (int j = 0; j < 4; ++j) acc2[i][j] = (f32x4){0.f, 0.f, 0.f, 0.f};
#pragma unroll
    for (int kk = 0; kk < 5; ++kk) {
      s16x8 af[6], bq[4];
#pragma unroll
      for (int mi = 0; mi < 6; ++mi) {
        int row = wr * 96 + mi * 16 + lr;
        af[mi] = *(const s16x8*)&U[row * 168 + (kk << 5) + (lk << 3)];
      }
#pragma unroll
      for (int ni = 0; ni < 4; ++ni)
        bq[ni] = *reinterpret_cast<const s16x8*>(
            &WuTp[(wc * 64 + ni * 16 + lr) * 160 + (kk << 5) + (lk << 3)]);
      __builtin_amdgcn_s_setprio(1);
#pragma unroll
      for (int mi = 0; mi < 6; ++mi)
#pragma unroll
        for (int ni = 0; ni < 4; ++ni)
          acc2[mi][ni] = __builtin_amdgcn_mfma_f32_16x16x32_bf16(af[mi], bq[ni], acc2[mi][ni], 0, 0, 0);
      __builtin_amdgcn_s_setprio(0);
    }
#pragma unroll
    for (int mi = 0; mi < 6; ++mi)
#pragma unroll
      for (int ni = 0; ni < 4; ++ni) {
        int col = wc * 64 + ni * 16 + lr;
#pragma unroll
        for (int r = 0; r < 4; ++r) {
          int row = row0 + wr * 96 + mi * 16 + lk * 4 + r;
          if (row < M3) Vub[(size_t)row * 128 + col] = f2bf(acc2[mi][ni][r]);
        }
      }
  }
}

// ---------------------------------------------------------------------------
// K2: feats_out = silu(Ab @ Wf + bf) -> out f32 + fob bf16.
// 3-buffer BK=32 counted-vmcnt pipeline (T4); coalesced LDS epilogue.
__global__ __launch_bounds__(256) void gemm_feats(
    const short* __restrict__ Ab, const short* __restrict__ WfT,
    const float* __restrict__ bfv, float* __restrict__ out,
    short* __restrict__ fob) {
  const int bid = blockIdx.x;
  const int swz = (bid & 7) * 391 + (bid >> 3);
  const int mt = swz >> 2, nt = swz & 3;
  const int row0 = mt << 7, n0 = nt << 7;
  const int t = threadIdx.x;
  const int lane = t & 63, wv = t >> 6;
  const int wr = wv >> 1, wc = wv & 1;
  const int lr = lane & 15, lk = lane >> 4;

  __shared__ __align__(16) short As[3][128 * 32];   // 24 KB
  __shared__ __align__(16) short Bs[3][128 * 32];   // 24 KB

  // staging: 2 A-chunks + 2 B-chunks per thread; LDS dest linear (cid*16B),
  // global source chunk permuted chs = ch ^ ((row>>1)&3)  [rule #21]
  const short* srcA[2];
  const short* srcB[2];
  int dofs[2];
#pragma unroll
  for (int j = 0; j < 2; ++j) {
    int cid = j * 256 + t;               // [0,512)
    int row = cid >> 2, ch = cid & 3;
    int chs = ch ^ ((row >> 1) & 3);
    srcA[j] = &Ab[(size_t)min(row0 + row, BATCH - 1) * KP + chs * 8];
    srcB[j] = &WfT[(size_t)(n0 + row) * KP + chs * 8];
    dofs[j] = cid * 8;
  }

  f32x4 acc[4][4];
#pragma unroll
  for (int i = 0; i < 4; ++i)
#pragma unroll
    for (int j = 0; j < 4; ++j) acc[i][j] = (f32x4){0.f, 0.f, 0.f, 0.f};

  auto STAGE = [&](int buf, int ks) {
    const int k0 = ks << 5;
#pragma unroll
    for (int j = 0; j < 2; ++j) glds16(srcA[j] + k0, &As[buf][dofs[j]]);
#pragma unroll
    for (int j = 0; j < 2; ++j) glds16(srcB[j] + k0, &Bs[buf][dofs[j]]);
  };
  auto COMPUTE = [&](int buf) {
    s16x8 af[4], bq[4];
#pragma unroll
    for (int mi = 0; mi < 4; ++mi) {
      int rw = wr * 64 + mi * 16 + lr;
      af[mi] = *(const s16x8*)&As[buf][rw * 32 + (lk ^ ((rw >> 1) & 3)) * 8];
    }
#pragma unroll
    for (int ni = 0; ni < 4; ++ni) {
      int rw = wc * 64 + ni * 16 + lr;
      bq[ni] = *(const s16x8*)&Bs[buf][rw * 32 + (lk ^ ((rw >> 1) & 3)) * 8];
    }
    __builtin_amdgcn_s_setprio(1);
#pragma unroll
    for (int mi = 0; mi < 4; ++mi)
#pragma unroll
      for (int ni = 0; ni < 4; ++ni)
        acc[mi][ni] = __builtin_amdgcn_mfma_f32_16x16x32_bf16(af[mi], bq[ni], acc[mi][ni], 0, 0, 0);
    __builtin_amdgcn_s_setprio(0);
  };

  STAGE(0, 0);
  STAGE(1, 1);
  for (int ks = 0; ks < 22; ++ks) {
    if (ks + 2 < 22) STAGE((ks + 2) % 3, ks + 2);
    if (ks < 20)      WAITBAR(8);
    else if (ks == 20) WAITBAR(4);
    else               WAITBAR(0);
    COMPUTE(ks % 3);
    RAWBAR();   // all waves done reading buf ks%3 before it's restaged
  }

  // coalesced epilogue: 4 groups of 32 rows staged through LDS (reuses As)
  float* Ls = (float*)&As[0][0];        // 16 KB per phase (32x128 f32)
#pragma unroll
  for (int g = 0; g < 4; ++g) {
    if (wr == (g >> 1)) {
      int miB = (g & 1) * 2;
#pragma unroll
      for (int m2 = 0; m2 < 2; ++m2) {
#pragma unroll
        for (int ni = 0; ni < 4; ++ni) {
          int colL = wc * 64 + ni * 16 + lr;
          float bb = bfv[n0 + colL];
#pragma unroll
          for (int rr = 0; rr < 4; ++rr) {
            int rowL = m2 * 16 + lk * 4 + rr;
            float x = acc[miB + m2][ni][rr] + bb;
            Ls[rowL * 128 + colL] = x / (1.f + __expf(-x));
          }
        }
      }
    }
    __syncthreads();
    {
      int rowL = t >> 3, seg = t & 7;
      int grow = row0 + g * 32 + rowL;
      if (grow < BATCH) {
        const float* p = &Ls[rowL * 128 + seg * 16];
        fl4 a = *(const fl4*)p, b = *(const fl4*)(p + 4);
        fl4 c = *(const fl4*)(p + 8), d = *(const fl4*)(p + 12);
        float* po = &out[(size_t)grow * 512 + n0 + seg * 16];
        *(fl4*)po = a; *(fl4*)(po + 4) = b; *(fl4*)(po + 8) = c; *(fl4*)(po + 12) = d;
        short* pf = &fob[(size_t)grow * 512 + n0 + seg * 16];
        *(s16x8*)pf = pack8(a, b);
        *(s16x8*)(pf + 8) = pack8(c, d);
      }
    }
    __syncthreads();
  }
}

// ---------------------------------------------------------------------------
// K3: gating GEMM + sigmoid*Vub -> vectors_out f32. Same counted-vmcnt pipeline.
__global__ __launch_bounds__(256) void gemm_gate(
    const short* __restrict__ fob, const short* __restrict__ WgT,
    const float* __restrict__ bg, const short* __restrict__ Vub,
    float* __restrict__ out) {
  const int bid = blockIdx.x;
  const int xcd = bid & 7, bidx = bid >> 3;
  const int swz = (xcd < 6 ? xcd * 98 : 6 * 98 + (xcd - 6) * 97) + bidx;
  const int row0 = swz << 7;
  const int t = threadIdx.x;
  const int lane = t & 63, wv = t >> 6;
  const int wr = wv >> 1, wc = wv & 1;
  const int lr = lane & 15, lk = lane >> 4;

  __shared__ __align__(16) short As[3][128 * 32];
  __shared__ __align__(16) short Bs[3][128 * 32];

  const short* srcA[2];
  const short* srcB[2];
  int dofs[2];
#pragma unroll
  for (int j = 0; j < 2; ++j) {
    int cid = j * 256 + t;
    int row = cid >> 2, ch = cid & 3;
    int chs = ch ^ ((row >> 1) & 3);
    srcA[j] = &fob[(size_t)min(row0 + row, BATCH - 1) * 512 + chs * 8];
    srcB[j] = &WgT[(size_t)row * 512 + chs * 8];
    dofs[j] = cid * 8;
  }

  f32x4 acc[4][4];
#pragma unroll
  for (int i = 0; i < 4; ++i)
#pragma unroll
    for (int j = 0; j < 4; ++j) acc[i][j] = (f32x4){0.f, 0.f, 0.f, 0.f};

  auto STAGE = [&](int buf, int ks) {
    const int k0 = ks << 5;
#pragma unroll
    for (int j = 0; j < 2; ++j) glds16(srcA[j] + k0, &As[buf][dofs[j]]);
#pragma unroll
    for (int j = 0; j < 2; ++j) glds16(srcB[j] + k0, &Bs[buf][dofs[j]]);
  };
  auto COMPUTE = [&](int buf) {
    s16x8 af[4], bq[4];
#pragma unroll
    for (int mi = 0; mi < 4; ++mi) {
      int rw = wr * 64 + mi * 16 + lr;
      af[mi] = *(const s16x8*)&As[buf][rw * 32 + (lk ^ ((rw >> 1) & 3)) * 8];
    }
#pragma unroll
    for (int ni = 0; ni < 4; ++ni) {
      int rw = wc * 64 + ni * 16 + lr;
      bq[ni] = *(const s16x8*)&Bs[buf][rw * 32 + (lk ^ ((rw >> 1) & 3)) * 8];
    }
    __builtin_amdgcn_s_setprio(1);
#pragma unroll
    for (int mi = 0; mi < 4; ++mi)
#pragma unroll
      for (int ni = 0; ni < 4; ++ni)
        acc[mi][ni] = __builtin_amdgcn_mfma_f32_16x16x32_bf16(af[mi], bq[ni], acc[mi][ni], 0, 0, 0);
    __builtin_amdgcn_s_setprio(0);
  };

  STAGE(0, 0);
  STAGE(1, 1);
  for (int ks = 0; ks < 16; ++ks) {
    if (ks + 2 < 16) STAGE((ks + 2) % 3, ks + 2);
    if (ks < 14)      WAITBAR(8);
    else if (ks == 14) WAITBAR(4);
    else               WAITBAR(0);
    COMPUTE(ks % 3);
    RAWBAR();
  }

#pragma unroll
  for (int ni = 0; ni < 4; ++ni) {
    int col = wc * 64 + ni * 16 + lr;
    float bb = bg[col];
#pragma unroll
    for (int mi = 0; mi < 4; ++mi) {
      int rbase = row0 + wr * 64 + mi * 16 + lk * 4;
#pragma unroll
      for (int rr = 0; rr < 4; ++rr) {
        int gr = rbase + rr;
        if (gr < BATCH) {
          float x = acc[mi][ni][rr] + bb;
          float gate = 1.f / (1.f + __expf(-x));
          size_t vb = (size_t)(3 * gr) * 128 + col;
          float* po = &out[VECBASE + ((size_t)gr * 128 + col) * 3];
          po[0] = gate * bf2f(Vub[vb]);
          po[1] = gate * bf2f(Vub[vb + 128]);
          po[2] = gate * bf2f(Vub[vb + 256]);
        }
      }
    }
  }
}

// ---------------------------------------------------------------------------
extern "C" void kernel_launch(void* const* d_in, const int* in_sizes, int n_in,
                              void* d_out, int out_size, void* d_ws, size_t ws_size,
                              hipStream_t stream) {
  const float* feats = (const float*)d_in[0];
  const float* vecs  = (const float*)d_in[1];
  const float* Wh    = (const float*)d_in[2];
  const float* Wcp   = (const float*)d_in[3];
  const float* Wu    = (const float*)d_in[4];
  const float* Wf    = (const float*)d_in[5];
  const float* bfv   = (const float*)d_in[6];
  const float* Wg    = (const float*)d_in[7];
  const float* bg    = (const float*)d_in[8];
  float* out = (float*)d_out;

  char* ws = (char*)d_ws;
  short* Ab   = (short*)ws;                                // 140,800,000 B
  short* Vub  = (short*)(ws + 140800000);                  //  76,800,000 B
  short* fob  = (short*)(ws + 217600000);                  // 102,400,000 B
  short* WfT  = (short*)(ws + 320000000);                  //     720,896 B
  short* WgT  = (short*)(ws + 320720896);                  //     131,072 B
  short* WB1  = (short*)(ws + 320851968);                  //      40,960 B
  short* WuTp = (short*)(ws + 320892928);                  //      40,960 B

  hipLaunchKernelGGL(prep_w,     dim3(2048), dim3(256), 0, stream,
                     feats, Wh, Wcp, Wu, Wf, Wg, Ab, WB1, WuTp, WfT, WgT);
  hipLaunchKernelGGL(geo_fused,  dim3(1563), dim3(256), 0, stream,
                     vecs, WB1, WuTp, Ab, Vub);
  hipLaunchKernelGGL(gemm_feats, dim3(3128), dim3(256), 0, stream,
                     Ab, WfT, bfv, out, fob);
  hipLaunchKernelGGL(gemm_gate,  dim3(782),  dim3(256), 0, stream,
                     fob, WgT, bg, Vub, out);
}

// Round 10
// 458.511 us; speedup vs baseline: 1.1888x; 1.1209x over previous
//
#include <hip/hip_runtime.h>

#define BATCH 100000
#define M3 300000            // 3*BATCH rows
#define VECBASE 51200000     // BATCH*512 floats; start of vectors_out region in d_out
#define KP 704               // padded K for Ab/WfT (656 -> 22*32)

typedef float fl4  __attribute__((ext_vector_type(4)));
typedef float f32x4 __attribute__((ext_vector_type(4)));
typedef short s16x4 __attribute__((ext_vector_type(4)));
typedef short s16x8 __attribute__((ext_vector_type(8)));

__device__ __forceinline__ short f2bf(float f) {
  unsigned int u = __float_as_uint(f);
  u += 0x7fffu + ((u >> 16) & 1u);
  return (short)(u >> 16);
}
__device__ __forceinline__ float bf2f(short s) {
  return __uint_as_float(((unsigned int)(unsigned short)s) << 16);
}
__device__ __forceinline__ s16x8 pack8(fl4 a, fl4 b) {
  s16x8 o;
  o[0] = f2bf(a[0]); o[1] = f2bf(a[1]); o[2] = f2bf(a[2]); o[3] = f2bf(a[3]);
  o[4] = f2bf(b[0]); o[5] = f2bf(b[1]); o[6] = f2bf(b[2]); o[7] = f2bf(b[3]);
  return o;
}
__device__ __forceinline__ void glds16(const void* g, void* l) {
  __builtin_amdgcn_global_load_lds((const __attribute__((address_space(1))) void*)g,
                                   (__attribute__((address_space(3))) void*)l, 16, 0, 0);
}
#define WAITBAR(N) asm volatile("s_waitcnt vmcnt(" #N ")\ns_barrier" ::: "memory")
#define RAWBAR()   asm volatile("s_barrier" ::: "memory")

// ---------------------------------------------------------------------------
// K0: prep. (a) feats -> Ab[:,0:512) bf16 (streaming); (b) weight transposes.
__global__ __launch_bounds__(256) void prep_w(
    const float* __restrict__ feats, const float* __restrict__ Wh,
    const float* __restrict__ Wcp, const float* __restrict__ Wu,
    const float* __restrict__ Wf, const float* __restrict__ Wg,
    short* __restrict__ Ab, short* __restrict__ WB1, short* __restrict__ WuTp,
    short* __restrict__ WfT, short* __restrict__ WgT) {
  const int tid = blockIdx.x * 256 + threadIdx.x;
  const int stride = gridDim.x * 256;
  for (int i = tid; i < 6400000; i += stride) {
    int b = i >> 6, kk = (i & 63) * 8;
    fl4 v0 = *reinterpret_cast<const fl4*>(&feats[(size_t)b * 512 + kk]);
    fl4 v1 = *reinterpret_cast<const fl4*>(&feats[(size_t)b * 512 + kk + 4]);
    *(s16x8*)&Ab[(size_t)b * KP + kk] = pack8(v0, v1);
  }
  for (int gid = tid; gid < 466944; gid += stride) {
    if (gid < 20480) {                       // WB1 [160][128]
      int n = gid >> 7, k = gid & 127;
      WB1[gid] = f2bf(n < 128 ? Wh[k * 128 + n] : Wcp[k * 32 + (n - 128)]);
    } else if (gid < 40960) {                // WuTp [128][160]
      int i = gid - 20480;
      int o = i / 160, k = i - o * 160;
      WuTp[i] = k < 144 ? f2bf(Wu[k * 128 + o]) : (short)0;
    } else if (gid < 401408) {               // WfT [512][704]
      int i = gid - 40960;
      int n = i / KP, k = i - n * KP;
      WfT[i] = k < 656 ? f2bf(Wf[k * 512 + n]) : (short)0;
    } else {                                 // WgT [128][512]
      int i = gid - 401408;
      int n = i >> 9, k = i & 511;
      WgT[i] = f2bf(Wg[k * 128 + n]);
    }
  }
}

// ---------------------------------------------------------------------------
// K1: geo_fused (unchanged from R9): GEMM1 + cross + norms->Ab + GEMM2->Vub.
__global__ __launch_bounds__(256) void geo_fused(
    const float* __restrict__ vecs, const short* __restrict__ WB1,
    const short* __restrict__ WuTp, short* __restrict__ Ab,
    short* __restrict__ Vub) {
  __shared__ __align__(16) short U[192 * 168];
  const int t = threadIdx.x;
  const int b0 = blockIdx.x * 64;
  const int row0 = blockIdx.x * 192;

#pragma unroll
  for (int it = 0; it < 8; ++it) {
    int fi = (it * 256 + t) * 12;
    int bl = fi / 384;
    int rem = fi - bl * 384;
    int v0 = rem / 3;
    int b = b0 + bl;
    fl4 x = (fl4){0.f, 0.f, 0.f, 0.f}, y = x, z = x;
    if (b < BATCH) {
      const float* p = &vecs[(size_t)b * 384 + rem];
      x = *(const fl4*)p; y = *(const fl4*)(p + 4); z = *(const fl4*)(p + 8);
    }
    float vc[3][4] = {{x[0], x[3], y[2], z[1]},
                      {x[1], y[0], y[3], z[2]},
                      {x[2], y[1], z[0], z[3]}};
#pragma unroll
    for (int c = 0; c < 3; ++c) {
      int row = bl * 3 + c;
      s16x4 q;
#pragma unroll
      for (int e = 0; e < 4; ++e) q[e] = f2bf(vc[c][e]);
      int off = (row << 8) + (v0 << 1);
      *(s16x4*)((char*)U + (off ^ ((row & 7) << 4))) = q;
    }
  }
  __syncthreads();

  const int lane = t & 63, wv = t >> 6;
  const int wr = wv >> 1, wc = wv & 1;
  const int lr = lane & 15, lk = lane >> 4;

  {  // GEMM1
    f32x4 acc[6][5];
#pragma unroll
    for (int i = 0; i < 6; ++i)
#pragma unroll
      for (int j = 0; j < 5; ++j) acc[i][j] = (f32x4){0.f, 0.f, 0.f, 0.f};
#pragma unroll
    for (int kk = 0; kk < 4; ++kk) {
      s16x8 af[6], bq[5];
#pragma unroll
      for (int mi = 0; mi < 6; ++mi) {
        int row = wr * 96 + mi * 16 + lr;
        int off = (row << 8) + (kk << 6) + (lk << 4);
        af[mi] = *(const s16x8*)((const char*)U + (off ^ ((row & 7) << 4)));
      }
#pragma unroll
      for (int ni = 0; ni < 5; ++ni)
        bq[ni] = *reinterpret_cast<const s16x8*>(
            &WB1[(wc * 80 + ni * 16 + lr) * 128 + (kk << 5) + (lk << 3)]);
      __builtin_amdgcn_s_setprio(1);
#pragma unroll
      for (int mi = 0; mi < 6; ++mi)
#pragma unroll
        for (int ni = 0; ni < 5; ++ni)
          acc[mi][ni] = __builtin_amdgcn_mfma_f32_16x16x32_bf16(af[mi], bq[ni], acc[mi][ni], 0, 0, 0);
      __builtin_amdgcn_s_setprio(0);
    }
    __syncthreads();
#pragma unroll
    for (int mi = 0; mi < 6; ++mi)
#pragma unroll
      for (int ni = 0; ni < 5; ++ni) {
        int col = wc * 80 + ni * 16 + lr;
#pragma unroll
        for (int r = 0; r < 4; ++r) {
          int row = wr * 96 + mi * 16 + lk * 4 + r;
          U[row * 168 + col] = f2bf(acc[mi][ni][r]);
        }
      }
  }
  __syncthreads();

  {  // cross
    int bl = t >> 2, pj = t & 3;
    int gb = b0 + bl;
    float shcp[4];
#pragma unroll
    for (int q = 0; q < 4; ++q) {
      int p = pj * 4 + q;
      float ax = bf2f(U[(bl * 3 + 0) * 168 + 128 + p]);
      float ay = bf2f(U[(bl * 3 + 1) * 168 + 128 + p]);
      float az = bf2f(U[(bl * 3 + 2) * 168 + 128 + p]);
      float bx = bf2f(U[(bl * 3 + 0) * 168 + 144 + p]);
      float by = bf2f(U[(bl * 3 + 1) * 168 + 144 + p]);
      float bz = bf2f(U[(bl * 3 + 2) * 168 + 144 + p]);
      float cx = ay * bz - az * by;
      float cy = az * bx - ax * bz;
      float cz = ax * by - ay * bx;
      U[(bl * 3 + 0) * 168 + 128 + p] = f2bf(cx);
      U[(bl * 3 + 1) * 168 + 128 + p] = f2bf(cy);
      U[(bl * 3 + 2) * 168 + 128 + p] = f2bf(cz);
      U[(bl * 3 + 0) * 168 + 144 + p] = 0;
      U[(bl * 3 + 1) * 168 + 144 + p] = 0;
      U[(bl * 3 + 2) * 168 + 144 + p] = 0;
      shcp[q] = sqrtf(fmaxf(cx * cx + cy * cy + cz * cz, 1e-8f));
    }
    if (gb < BATCH) {
#pragma unroll
      for (int q = 0; q < 4; ++q)
        Ab[(size_t)gb * KP + 512 + 128 + pj * 4 + q] = f2bf(shcp[q]);
#pragma unroll
      for (int z = 0; z < 12; ++z)
        Ab[(size_t)gb * KP + 512 + 144 + pj * 12 + z] = 0;
    }
  }
  {  // norms k<128
    int bl = t >> 2, kq = t & 3;
    int gb = b0 + bl;
    if (gb < BATCH) {
#pragma unroll
      for (int j = 0; j < 4; ++j) {
        int k = kq * 32 + j * 8;
        s16x8 r0 = *(const s16x8*)&U[(bl * 3 + 0) * 168 + k];
        s16x8 r1 = *(const s16x8*)&U[(bl * 3 + 1) * 168 + k];
        s16x8 r2 = *(const s16x8*)&U[(bl * 3 + 2) * 168 + k];
        s16x8 o;
#pragma unroll
        for (int e = 0; e < 8; ++e) {
          float x = bf2f(r0[e]), y = bf2f(r1[e]), z = bf2f(r2[e]);
          o[e] = f2bf(sqrtf(fmaxf(x * x + y * y + z * z, 1e-8f)));
        }
        *(s16x8*)&Ab[(size_t)gb * KP + 512 + k] = o;
      }
    }
  }
  __syncthreads();

  {  // GEMM2
    f32x4 acc2[6][4];
#pragma unroll
    for (int i = 0; i < 6; ++i)
#pragma unroll
      for (int j = 0; j < 4; ++j) acc2[i][j] = (f32x4){0.f, 0.f, 0.f, 0.f};
#pragma unroll
    for (int kk = 0; kk < 5; ++kk) {
      s16x8 af[6], bq[4];
#pragma unroll
      for (int mi = 0; mi < 6; ++mi) {
        int row = wr * 96 + mi * 16 + lr;
        af[mi] = *(const s16x8*)&U[row * 168 + (kk << 5) + (lk << 3)];
      }
#pragma unroll
      for (int ni = 0; ni < 4; ++ni)
        bq[ni] = *reinterpret_cast<const s16x8*>(
            &WuTp[(wc * 64 + ni * 16 + lr) * 160 + (kk << 5) + (lk << 3)]);
      __builtin_amdgcn_s_setprio(1);
#pragma unroll
      for (int mi = 0; mi < 6; ++mi)
#pragma unroll
        for (int ni = 0; ni < 4; ++ni)
          acc2[mi][ni] = __builtin_amdgcn_mfma_f32_16x16x32_bf16(af[mi], bq[ni], acc2[mi][ni], 0, 0, 0);
      __builtin_amdgcn_s_setprio(0);
    }
#pragma unroll
    for (int mi = 0; mi < 6; ++mi)
#pragma unroll
      for (int ni = 0; ni < 4; ++ni) {
        int col = wc * 64 + ni * 16 + lr;
#pragma unroll
        for (int r = 0; r < 4; ++r) {
          int row = row0 + wr * 96 + mi * 16 + lk * 4 + r;
          if (row < M3) Vub[(size_t)row * 128 + col] = f2bf(acc2[mi][ni][r]);
        }
      }
  }
}

// ---------------------------------------------------------------------------
// K2: feats_out = silu(Ab @ Wf + bf) -> out f32 + fob bf16.
// 512 threads, 128x256 tile (8 waves 2x4), BK=32 single-buffered m97-style
// glds staging; 2 blocks/CU -> 16 waves/CU of TLP. Coalesced LDS epilogue.
__global__ __launch_bounds__(512, 4) void gemm_feats(
    const short* __restrict__ Ab, const short* __restrict__ WfT,
    const float* __restrict__ bfv, float* __restrict__ out,
    short* __restrict__ fob) {
  const int bid = blockIdx.x;
  // bijective XCD remap: 1564 = 8*195 + 4
  const int xcd = bid & 7, bi = bid >> 3;
  const int swz = (xcd < 4 ? xcd * 196 : 784 + (xcd - 4) * 195) + bi;
  const int mt = swz >> 1, nt = swz & 1;
  const int row0 = mt << 7, n0 = nt << 8;
  const int t = threadIdx.x;
  const int lane = t & 63, wv = t >> 6;
  const int wr = wv >> 2, wc = wv & 3;        // 2 x 4 wave grid
  const int lr = lane & 15, lk = lane >> 4;

  __shared__ __align__(16) short S[(128 + 256) * 32];   // 24 KB: As | Bs; epilogue reuses
  short* As = S;                 // [128][32]
  short* Bs = S + 4096;          // [256][32]

  // A staging: 512 chunks of 16B, 1/thread; source chunk permuted chs=ch^((row>>1)&3)
  const int arow = t >> 2, ach = t & 3;
  const short* srcA = &Ab[(size_t)min(row0 + arow, BATCH - 1) * KP + (ach ^ ((arow >> 1) & 3)) * 8];
  const int adof = t * 8;
  // B staging: 1024 chunks, 2/thread
  const short* srcB[2];
  int bdof[2];
#pragma unroll
  for (int j = 0; j < 2; ++j) {
    int cid = j * 512 + t;
    int brow = cid >> 2, bch = cid & 3;
    srcB[j] = &WfT[(size_t)(n0 + brow) * KP + (bch ^ ((brow >> 1) & 3)) * 8];
    bdof[j] = cid * 8;
  }

  f32x4 acc[4][4];
#pragma unroll
  for (int i = 0; i < 4; ++i)
#pragma unroll
    for (int j = 0; j < 4; ++j) acc[i][j] = (f32x4){0.f, 0.f, 0.f, 0.f};

  for (int ks = 0; ks < 22; ++ks) {
    const int k0 = ks << 5;
    __syncthreads();
    glds16(srcA + k0, &As[adof]);
    glds16(srcB[0] + k0, &Bs[bdof[0]]);
    glds16(srcB[1] + k0, &Bs[bdof[1]]);
    __syncthreads();
    s16x8 af[4], bq[4];
#pragma unroll
    for (int mi = 0; mi < 4; ++mi) {
      int rw = wr * 64 + mi * 16 + lr;
      af[mi] = *(const s16x8*)&As[rw * 32 + (lk ^ ((rw >> 1) & 3)) * 8];
    }
#pragma unroll
    for (int ni = 0; ni < 4; ++ni) {
      int rn = wc * 64 + ni * 16 + lr;
      bq[ni] = *(const s16x8*)&Bs[rn * 32 + (lk ^ ((rn >> 1) & 3)) * 8];
    }
    __builtin_amdgcn_s_setprio(1);
#pragma unroll
    for (int mi = 0; mi < 4; ++mi)
#pragma unroll
      for (int ni = 0; ni < 4; ++ni)
        acc[mi][ni] = __builtin_amdgcn_mfma_f32_16x16x32_bf16(af[mi], bq[ni], acc[mi][ni], 0, 0, 0);
    __builtin_amdgcn_s_setprio(0);
  }

  // coalesced epilogue: 8 groups of 16 rows staged through LDS (16KB of S)
  float* Ls = (float*)S;
#pragma unroll
  for (int g = 0; g < 8; ++g) {
    __syncthreads();
    if (wr == (g >> 2)) {
      int mi = g & 3;
#pragma unroll
      for (int ni = 0; ni < 4; ++ni) {
        int colL = wc * 64 + ni * 16 + lr;
        float bb = bfv[n0 + colL];
#pragma unroll
        for (int rr = 0; rr < 4; ++rr) {
          float x = acc[mi][ni][rr] + bb;
          Ls[(lk * 4 + rr) * 256 + colL] = x / (1.f + __expf(-x));
        }
      }
    }
    __syncthreads();
    {
      int rowL = t >> 5, seg = t & 31;
      int grow = row0 + g * 16 + rowL;
      if (grow < BATCH) {
        const float* p = &Ls[rowL * 256 + seg * 8];
        fl4 a = *(const fl4*)p, b = *(const fl4*)(p + 4);
        float* po = &out[(size_t)grow * 512 + n0 + seg * 8];
        *(fl4*)po = a; *(fl4*)(po + 4) = b;
        *(s16x8*)&fob[(size_t)grow * 512 + n0 + seg * 8] = pack8(a, b);
      }
    }
  }
}

// ---------------------------------------------------------------------------
// K3: gating GEMM + sigmoid*Vub -> vectors_out f32. (unchanged from R9)
__global__ __launch_bounds__(256) void gemm_gate(
    const short* __restrict__ fob, const short* __restrict__ WgT,
    const float* __restrict__ bg, const short* __restrict__ Vub,
    float* __restrict__ out) {
  const int bid = blockIdx.x;
  const int xcd = bid & 7, bidx = bid >> 3;
  const int swz = (xcd < 6 ? xcd * 98 : 6 * 98 + (xcd - 6) * 97) + bidx;
  const int row0 = swz << 7;
  const int t = threadIdx.x;
  const int lane = t & 63, wv = t >> 6;
  const int wr = wv >> 1, wc = wv & 1;
  const int lr = lane & 15, lk = lane >> 4;

  __shared__ __align__(16) short As[3][128 * 32];
  __shared__ __align__(16) short Bs[3][128 * 32];

  const short* srcA[2];
  const short* srcB[2];
  int dofs[2];
#pragma unroll
  for (int j = 0; j < 2; ++j) {
    int cid = j * 256 + t;
    int row = cid >> 2, ch = cid & 3;
    int chs = ch ^ ((row >> 1) & 3);
    srcA[j] = &fob[(size_t)min(row0 + row, BATCH - 1) * 512 + chs * 8];
    srcB[j] = &WgT[(size_t)row * 512 + chs * 8];
    dofs[j] = cid * 8;
  }

  f32x4 acc[4][4];
#pragma unroll
  for (int i = 0; i < 4; ++i)
#pragma unroll
    for (int j = 0; j < 4; ++j) acc[i][j] = (f32x4){0.f, 0.f, 0.f, 0.f};

  auto STAGE = [&](int buf, int ks) {
    const int k0 = ks << 5;
#pragma unroll
    for (int j = 0; j < 2; ++j) glds16(srcA[j] + k0, &As[buf][dofs[j]]);
#pragma unroll
    for (int j = 0; j < 2; ++j) glds16(srcB[j] + k0, &Bs[buf][dofs[j]]);
  };
  auto COMPUTE = [&](int buf) {
    s16x8 af[4], bq[4];
#pragma unroll
    for (int mi = 0; mi < 4; ++mi) {
      int rw = wr * 64 + mi * 16 + lr;
      af[mi] = *(const s16x8*)&As[buf][rw * 32 + (lk ^ ((rw >> 1) & 3)) * 8];
    }
#pragma unroll
    for (int ni = 0; ni < 4; ++ni) {
      int rw = wc * 64 + ni * 16 + lr;
      bq[ni] = *(const s16x8*)&Bs[buf][rw * 32 + (lk ^ ((rw >> 1) & 3)) * 8];
    }
    __builtin_amdgcn_s_setprio(1);
#pragma unroll
    for (int mi = 0; mi < 4; ++mi)
#pragma unroll
      for (int ni = 0; ni < 4; ++ni)
        acc[mi][ni] = __builtin_amdgcn_mfma_f32_16x16x32_bf16(af[mi], bq[ni], acc[mi][ni], 0, 0, 0);
    __builtin_amdgcn_s_setprio(0);
  };

  STAGE(0, 0);
  STAGE(1, 1);
  for (int ks = 0; ks < 16; ++ks) {
    if (ks + 2 < 16) STAGE((ks + 2) % 3, ks + 2);
    if (ks < 14)      WAITBAR(8);
    else if (ks == 14) WAITBAR(4);
    else               WAITBAR(0);
    COMPUTE(ks % 3);
    RAWBAR();
  }

#pragma unroll
  for (int ni = 0; ni < 4; ++ni) {
    int col = wc * 64 + ni * 16 + lr;
    float bb = bg[col];
#pragma unroll
    for (int mi = 0; mi < 4; ++mi) {
      int rbase = row0 + wr * 64 + mi * 16 + lk * 4;
#pragma unroll
      for (int rr = 0; rr < 4; ++rr) {
        int gr = rbase + rr;
        if (gr < BATCH) {
          float x = acc[mi][ni][rr] + bb;
          float gate = 1.f / (1.f + __expf(-x));
          size_t vb = (size_t)(3 * gr) * 128 + col;
          float* po = &out[VECBASE + ((size_t)gr * 128 + col) * 3];
          po[0] = gate * bf2f(Vub[vb]);
          po[1] = gate * bf2f(Vub[vb + 128]);
          po[2] = gate * bf2f(Vub[vb + 256]);
        }
      }
    }
  }
}

// ---------------------------------------------------------------------------
extern "C" void kernel_launch(void* const* d_in, const int* in_sizes, int n_in,
                              void* d_out, int out_size, void* d_ws, size_t ws_size,
                              hipStream_t stream) {
  const float* feats = (const float*)d_in[0];
  const float* vecs  = (const float*)d_in[1];
  const float* Wh    = (const float*)d_in[2];
  const float* Wcp   = (const float*)d_in[3];
  const float* Wu    = (const float*)d_in[4];
  const float* Wf    = (const float*)d_in[5];
  const float* bfv   = (const float*)d_in[6];
  const float* Wg    = (const float*)d_in[7];
  const float* bg    = (const float*)d_in[8];
  float* out = (float*)d_out;

  char* ws = (char*)d_ws;
  short* Ab   = (short*)ws;                                // 140,800,000 B
  short* Vub  = (short*)(ws + 140800000);                  //  76,800,000 B
  short* fob  = (short*)(ws + 217600000);                  // 102,400,000 B
  short* WfT  = (short*)(ws + 320000000);                  //     720,896 B
  short* WgT  = (short*)(ws + 320720896);                  //     131,072 B
  short* WB1  = (short*)(ws + 320851968);                  //      40,960 B
  short* WuTp = (short*)(ws + 320892928);                  //      40,960 B

  hipLaunchKernelGGL(prep_w,     dim3(2048), dim3(256), 0, stream,
                     feats, Wh, Wcp, Wu, Wf, Wg, Ab, WB1, WuTp, WfT, WgT);
  hipLaunchKernelGGL(geo_fused,  dim3(1563), dim3(256), 0, stream,
                     vecs, WB1, WuTp, Ab, Vub);
  hipLaunchKernelGGL(gemm_feats, dim3(1564), dim3(512), 0, stream,
                     Ab, WfT, bfv, out, fob);
  hipLaunchKernelGGL(gemm_gate,  dim3(782),  dim3(256), 0, stream,
                     fob, WgT, bg, Vub, out);
}

// Round 11
// 432.913 us; speedup vs baseline: 1.2591x; 1.0591x over previous
//
#include <hip/hip_runtime.h>

#define BATCH 100000
#define M3 300000            // 3*BATCH rows
#define VECBASE 51200000     // BATCH*512 floats; start of vectors_out region in d_out
#define KP 704               // padded K for Ab/WfT (656 -> 11*64)

typedef float fl4  __attribute__((ext_vector_type(4)));
typedef float f32x4 __attribute__((ext_vector_type(4)));
typedef short s16x4 __attribute__((ext_vector_type(4)));
typedef short s16x8 __attribute__((ext_vector_type(8)));

__device__ __forceinline__ short f2bf(float f) {
  unsigned int u = __float_as_uint(f);
  u += 0x7fffu + ((u >> 16) & 1u);
  return (short)(u >> 16);
}
__device__ __forceinline__ float bf2f(short s) {
  return __uint_as_float(((unsigned int)(unsigned short)s) << 16);
}
__device__ __forceinline__ s16x8 pack8(fl4 a, fl4 b) {
  s16x8 o;
  o[0] = f2bf(a[0]); o[1] = f2bf(a[1]); o[2] = f2bf(a[2]); o[3] = f2bf(a[3]);
  o[4] = f2bf(b[0]); o[5] = f2bf(b[1]); o[6] = f2bf(b[2]); o[7] = f2bf(b[3]);
  return o;
}
__device__ __forceinline__ void glds16(const void* g, void* l) {
  __builtin_amdgcn_global_load_lds((const __attribute__((address_space(1))) void*)g,
                                   (__attribute__((address_space(3))) void*)l, 16, 0, 0);
}

// ---------------------------------------------------------------------------
// K0: prep. (a) feats -> Ab[:,0:512) bf16 (streaming); (b) weight transposes.
__global__ __launch_bounds__(256) void prep_w(
    const float* __restrict__ feats, const float* __restrict__ Wh,
    const float* __restrict__ Wcp, const float* __restrict__ Wu,
    const float* __restrict__ Wf, const float* __restrict__ Wg,
    short* __restrict__ Ab, short* __restrict__ WB1, short* __restrict__ WuTp,
    short* __restrict__ WfT, short* __restrict__ WgT) {
  const int tid = blockIdx.x * 256 + threadIdx.x;
  const int stride = gridDim.x * 256;
  for (int i = tid; i < 6400000; i += stride) {
    int b = i >> 6, kk = (i & 63) * 8;
    fl4 v0 = *reinterpret_cast<const fl4*>(&feats[(size_t)b * 512 + kk]);
    fl4 v1 = *reinterpret_cast<const fl4*>(&feats[(size_t)b * 512 + kk + 4]);
    *(s16x8*)&Ab[(size_t)b * KP + kk] = pack8(v0, v1);
  }
  for (int gid = tid; gid < 466944; gid += stride) {
    if (gid < 20480) {                       // WB1 [160][128]
      int n = gid >> 7, k = gid & 127;
      WB1[gid] = f2bf(n < 128 ? Wh[k * 128 + n] : Wcp[k * 32 + (n - 128)]);
    } else if (gid < 40960) {                // WuTp [128][160]
      int i = gid - 20480;
      int o = i / 160, k = i - o * 160;
      WuTp[i] = k < 144 ? f2bf(Wu[k * 128 + o]) : (short)0;
    } else if (gid < 401408) {               // WfT [512][704]
      int i = gid - 40960;
      int n = i / KP, k = i - n * KP;
      WfT[i] = k < 656 ? f2bf(Wf[k * 512 + n]) : (short)0;
    } else {                                 // WgT [128][512]
      int i = gid - 401408;
      int n = i >> 9, k = i & 511;
      WgT[i] = f2bf(Wg[k * 128 + n]);
    }
  }
}

// ---------------------------------------------------------------------------
// K1: geo_fused (unchanged from R10): GEMM1 + cross + norms->Ab + GEMM2->Vub.
__global__ __launch_bounds__(256) void geo_fused(
    const float* __restrict__ vecs, const short* __restrict__ WB1,
    const short* __restrict__ WuTp, short* __restrict__ Ab,
    short* __restrict__ Vub) {
  __shared__ __align__(16) short U[192 * 168];
  const int t = threadIdx.x;
  const int b0 = blockIdx.x * 64;
  const int row0 = blockIdx.x * 192;

#pragma unroll
  for (int it = 0; it < 8; ++it) {
    int fi = (it * 256 + t) * 12;
    int bl = fi / 384;
    int rem = fi - bl * 384;
    int v0 = rem / 3;
    int b = b0 + bl;
    fl4 x = (fl4){0.f, 0.f, 0.f, 0.f}, y = x, z = x;
    if (b < BATCH) {
      const float* p = &vecs[(size_t)b * 384 + rem];
      x = *(const fl4*)p; y = *(const fl4*)(p + 4); z = *(const fl4*)(p + 8);
    }
    float vc[3][4] = {{x[0], x[3], y[2], z[1]},
                      {x[1], y[0], y[3], z[2]},
                      {x[2], y[1], z[0], z[3]}};
#pragma unroll
    for (int c = 0; c < 3; ++c) {
      int row = bl * 3 + c;
      s16x4 q;
#pragma unroll
      for (int e = 0; e < 4; ++e) q[e] = f2bf(vc[c][e]);
      int off = (row << 8) + (v0 << 1);
      *(s16x4*)((char*)U + (off ^ ((row & 7) << 4))) = q;
    }
  }
  __syncthreads();

  const int lane = t & 63, wv = t >> 6;
  const int wr = wv >> 1, wc = wv & 1;
  const int lr = lane & 15, lk = lane >> 4;

  {  // GEMM1
    f32x4 acc[6][5];
#pragma unroll
    for (int i = 0; i < 6; ++i)
#pragma unroll
      for (int j = 0; j < 5; ++j) acc[i][j] = (f32x4){0.f, 0.f, 0.f, 0.f};
#pragma unroll
    for (int kk = 0; kk < 4; ++kk) {
      s16x8 af[6], bq[5];
#pragma unroll
      for (int mi = 0; mi < 6; ++mi) {
        int row = wr * 96 + mi * 16 + lr;
        int off = (row << 8) + (kk << 6) + (lk << 4);
        af[mi] = *(const s16x8*)((const char*)U + (off ^ ((row & 7) << 4)));
      }
#pragma unroll
      for (int ni = 0; ni < 5; ++ni)
        bq[ni] = *reinterpret_cast<const s16x8*>(
            &WB1[(wc * 80 + ni * 16 + lr) * 128 + (kk << 5) + (lk << 3)]);
      __builtin_amdgcn_s_setprio(1);
#pragma unroll
      for (int mi = 0; mi < 6; ++mi)
#pragma unroll
        for (int ni = 0; ni < 5; ++ni)
          acc[mi][ni] = __builtin_amdgcn_mfma_f32_16x16x32_bf16(af[mi], bq[ni], acc[mi][ni], 0, 0, 0);
      __builtin_amdgcn_s_setprio(0);
    }
    __syncthreads();
#pragma unroll
    for (int mi = 0; mi < 6; ++mi)
#pragma unroll
      for (int ni = 0; ni < 5; ++ni) {
        int col = wc * 80 + ni * 16 + lr;
#pragma unroll
        for (int r = 0; r < 4; ++r) {
          int row = wr * 96 + mi * 16 + lk * 4 + r;
          U[row * 168 + col] = f2bf(acc[mi][ni][r]);
        }
      }
  }
  __syncthreads();

  {  // cross
    int bl = t >> 2, pj = t & 3;
    int gb = b0 + bl;
    float shcp[4];
#pragma unroll
    for (int q = 0; q < 4; ++q) {
      int p = pj * 4 + q;
      float ax = bf2f(U[(bl * 3 + 0) * 168 + 128 + p]);
      float ay = bf2f(U[(bl * 3 + 1) * 168 + 128 + p]);
      float az = bf2f(U[(bl * 3 + 2) * 168 + 128 + p]);
      float bx = bf2f(U[(bl * 3 + 0) * 168 + 144 + p]);
      float by = bf2f(U[(bl * 3 + 1) * 168 + 144 + p]);
      float bz = bf2f(U[(bl * 3 + 2) * 168 + 144 + p]);
      float cx = ay * bz - az * by;
      float cy = az * bx - ax * bz;
      float cz = ax * by - ay * bx;
      U[(bl * 3 + 0) * 168 + 128 + p] = f2bf(cx);
      U[(bl * 3 + 1) * 168 + 128 + p] = f2bf(cy);
      U[(bl * 3 + 2) * 168 + 128 + p] = f2bf(cz);
      U[(bl * 3 + 0) * 168 + 144 + p] = 0;
      U[(bl * 3 + 1) * 168 + 144 + p] = 0;
      U[(bl * 3 + 2) * 168 + 144 + p] = 0;
      shcp[q] = sqrtf(fmaxf(cx * cx + cy * cy + cz * cz, 1e-8f));
    }
    if (gb < BATCH) {
#pragma unroll
      for (int q = 0; q < 4; ++q)
        Ab[(size_t)gb * KP + 512 + 128 + pj * 4 + q] = f2bf(shcp[q]);
#pragma unroll
      for (int z = 0; z < 12; ++z)
        Ab[(size_t)gb * KP + 512 + 144 + pj * 12 + z] = 0;
    }
  }
  {  // norms k<128
    int bl = t >> 2, kq = t & 3;
    int gb = b0 + bl;
    if (gb < BATCH) {
#pragma unroll
      for (int j = 0; j < 4; ++j) {
        int k = kq * 32 + j * 8;
        s16x8 r0 = *(const s16x8*)&U[(bl * 3 + 0) * 168 + k];
        s16x8 r1 = *(const s16x8*)&U[(bl * 3 + 1) * 168 + k];
        s16x8 r2 = *(const s16x8*)&U[(bl * 3 + 2) * 168 + k];
        s16x8 o;
#pragma unroll
        for (int e = 0; e < 8; ++e) {
          float x = bf2f(r0[e]), y = bf2f(r1[e]), z = bf2f(r2[e]);
          o[e] = f2bf(sqrtf(fmaxf(x * x + y * y + z * z, 1e-8f)));
        }
        *(s16x8*)&Ab[(size_t)gb * KP + 512 + k] = o;
      }
    }
  }
  __syncthreads();

  {  // GEMM2
    f32x4 acc2[6][4];
#pragma unroll
    for (int i = 0; i < 6; ++i)
#pragma unroll
      for (int j = 0; j < 4; ++j) acc2[i][j] = (f32x4){0.f, 0.f, 0.f, 0.f};
#pragma unroll
    for (int kk = 0; kk < 5; ++kk) {
      s16x8 af[6], bq[4];
#pragma unroll
      for (int mi = 0; mi < 6; ++mi) {
        int row = wr * 96 + mi * 16 + lr;
        af[mi] = *(const s16x8*)&U[row * 168 + (kk << 5) + (lk << 3)];
      }
#pragma unroll
      for (int ni = 0; ni < 4; ++ni)
        bq[ni] = *reinterpret_cast<const s16x8*>(
            &WuTp[(wc * 64 + ni * 16 + lr) * 160 + (kk << 5) + (lk << 3)]);
      __builtin_amdgcn_s_setprio(1);
#pragma unroll
      for (int mi = 0; mi < 6; ++mi)
#pragma unroll
        for (int ni = 0; ni < 4; ++ni)
          acc2[mi][ni] = __builtin_amdgcn_mfma_f32_16x16x32_bf16(af[mi], bq[ni], acc2[mi][ni], 0, 0, 0);
      __builtin_amdgcn_s_setprio(0);
    }
#pragma unroll
    for (int mi = 0; mi < 6; ++mi)
#pragma unroll
      for (int ni = 0; ni < 4; ++ni) {
        int col = wc * 64 + ni * 16 + lr;
#pragma unroll
        for (int r = 0; r < 4; ++r) {
          int row = row0 + wr * 96 + mi * 16 + lk * 4 + r;
          if (row < M3) Vub[(size_t)row * 128 + col] = f2bf(acc2[mi][ni][r]);
        }
      }
  }
}

// ---------------------------------------------------------------------------
// K2: feats_out = silu(Ab @ Wf + bf) -> out f32 + fob bf16.
// 512 threads, 128x256 tile (2x4 waves), BK=64 single-buffered glds staging
// (11 K-steps), 8-chunk-row source-permuted swizzle. Coalesced LDS epilogue.
__global__ __launch_bounds__(512, 4) void gemm_feats(
    const short* __restrict__ Ab, const short* __restrict__ WfT,
    const float* __restrict__ bfv, float* __restrict__ out,
    short* __restrict__ fob) {
  const int bid = blockIdx.x;
  // bijective XCD remap: 1564 = 8*195 + 4
  const int xcd = bid & 7, bi = bid >> 3;
  const int swz = (xcd < 4 ? xcd * 196 : 784 + (xcd - 4) * 195) + bi;
  const int mt = swz >> 1, nt = swz & 1;
  const int row0 = mt << 7, n0 = nt << 8;
  const int t = threadIdx.x;
  const int lane = t & 63, wv = t >> 6;
  const int wr = wv >> 2, wc = wv & 3;        // 2 x 4 wave grid
  const int lr = lane & 15, lk = lane >> 4;

  __shared__ __align__(16) short S[(128 + 256) * 64];   // 48 KB: As | Bs
  short* As = S;                 // [128][64]
  short* Bs = S + 128 * 64;      // [256][64]

  // A: 1024 chunks (128 rows x 8), 2/thread; B: 2048 chunks (256 rows x 8), 4/thread
  const short* srcA[2]; int adof[2];
#pragma unroll
  for (int j = 0; j < 2; ++j) {
    int cid = j * 512 + t;
    int row = cid >> 3, ch = cid & 7;
    srcA[j] = &Ab[(size_t)min(row0 + row, BATCH - 1) * KP + (ch ^ (row & 7)) * 8];
    adof[j] = cid * 8;
  }
  const short* srcB[4]; int bdof[4];
#pragma unroll
  for (int j = 0; j < 4; ++j) {
    int cid = j * 512 + t;
    int row = cid >> 3, ch = cid & 7;
    srcB[j] = &WfT[(size_t)(n0 + row) * KP + (ch ^ (row & 7)) * 8];
    bdof[j] = cid * 8;
  }

  f32x4 acc[4][4];
#pragma unroll
  for (int i = 0; i < 4; ++i)
#pragma unroll
    for (int j = 0; j < 4; ++j) acc[i][j] = (f32x4){0.f, 0.f, 0.f, 0.f};

  for (int ks = 0; ks < 11; ++ks) {
    const int k0 = ks << 6;
    __syncthreads();
    glds16(srcA[0] + k0, &As[adof[0]]);
    glds16(srcA[1] + k0, &As[adof[1]]);
#pragma unroll
    for (int j = 0; j < 4; ++j) glds16(srcB[j] + k0, &Bs[bdof[j]]);
    __syncthreads();
#pragma unroll
    for (int kk = 0; kk < 2; ++kk) {
      s16x8 af[4], bq[4];
#pragma unroll
      for (int mi = 0; mi < 4; ++mi) {
        int rw = wr * 64 + mi * 16 + lr;
        af[mi] = *(const s16x8*)&As[rw * 64 + (((kk << 2) + lk) ^ (rw & 7)) * 8];
      }
#pragma unroll
      for (int ni = 0; ni < 4; ++ni) {
        int rn = wc * 64 + ni * 16 + lr;
        bq[ni] = *(const s16x8*)&Bs[rn * 64 + (((kk << 2) + lk) ^ (rn & 7)) * 8];
      }
      __builtin_amdgcn_s_setprio(1);
#pragma unroll
      for (int mi = 0; mi < 4; ++mi)
#pragma unroll
        for (int ni = 0; ni < 4; ++ni)
          acc[mi][ni] = __builtin_amdgcn_mfma_f32_16x16x32_bf16(af[mi], bq[ni], acc[mi][ni], 0, 0, 0);
      __builtin_amdgcn_s_setprio(0);
    }
  }

  // coalesced epilogue: 8 groups of 16 rows staged through LDS (16KB of S)
  float* Ls = (float*)S;
#pragma unroll
  for (int g = 0; g < 8; ++g) {
    __syncthreads();
    if (wr == (g >> 2)) {
      int mi = g & 3;
#pragma unroll
      for (int ni = 0; ni < 4; ++ni) {
        int colL = wc * 64 + ni * 16 + lr;
        float bb = bfv[n0 + colL];
#pragma unroll
        for (int rr = 0; rr < 4; ++rr) {
          float x = acc[mi][ni][rr] + bb;
          Ls[(lk * 4 + rr) * 256 + colL] = x / (1.f + __expf(-x));
        }
      }
    }
    __syncthreads();
    {
      int rowL = t >> 5, seg = t & 31;
      int grow = row0 + g * 16 + rowL;
      if (grow < BATCH) {
        const float* p = &Ls[rowL * 256 + seg * 8];
        fl4 a = *(const fl4*)p, b = *(const fl4*)(p + 4);
        float* po = &out[(size_t)grow * 512 + n0 + seg * 8];
        *(fl4*)po = a; *(fl4*)(po + 4) = b;
        *(s16x8*)&fob[(size_t)grow * 512 + n0 + seg * 8] = pack8(a, b);
      }
    }
  }
}

// ---------------------------------------------------------------------------
// K3: gating GEMM + sigmoid*Vub -> vectors_out f32.
// 512 threads, 256x128 tile (4x2 waves), BK=64 single-buffered (8 K-steps).
__global__ __launch_bounds__(512, 4) void gemm_gate(
    const short* __restrict__ fob, const short* __restrict__ WgT,
    const float* __restrict__ bg, const short* __restrict__ Vub,
    float* __restrict__ out) {
  const int bid = blockIdx.x;
  // bijective XCD remap: 391 = 8*48 + 7
  const int xcd = bid & 7, bi = bid >> 3;
  const int swz = (xcd < 7 ? xcd * 49 : 343 + (xcd - 7) * 48) + bi;
  const int row0 = swz << 8;
  const int t = threadIdx.x;
  const int lane = t & 63, wv = t >> 6;
  const int wr = wv >> 1, wc = wv & 1;        // 4 x 2 wave grid
  const int lr = lane & 15, lk = lane >> 4;

  __shared__ __align__(16) short S[(256 + 128) * 64];   // 48 KB: As | Bs
  short* As = S;                 // [256][64]
  short* Bs = S + 256 * 64;      // [128][64]

  // A: 2048 chunks (256 rows x 8), 4/thread; B: 1024 chunks (128 rows x 8), 2/thread
  const short* srcA[4]; int adof[4];
#pragma unroll
  for (int j = 0; j < 4; ++j) {
    int cid = j * 512 + t;
    int row = cid >> 3, ch = cid & 7;
    srcA[j] = &fob[(size_t)min(row0 + row, BATCH - 1) * 512 + (ch ^ (row & 7)) * 8];
    adof[j] = cid * 8;
  }
  const short* srcB[2]; int bdof[2];
#pragma unroll
  for (int j = 0; j < 2; ++j) {
    int cid = j * 512 + t;
    int row = cid >> 3, ch = cid & 7;
    srcB[j] = &WgT[(size_t)row * 512 + (ch ^ (row & 7)) * 8];
    bdof[j] = cid * 8;
  }

  f32x4 acc[4][4];
#pragma unroll
  for (int i = 0; i < 4; ++i)
#pragma unroll
    for (int j = 0; j < 4; ++j) acc[i][j] = (f32x4){0.f, 0.f, 0.f, 0.f};

  for (int ks = 0; ks < 8; ++ks) {
    const int k0 = ks << 6;
    __syncthreads();
#pragma unroll
    for (int j = 0; j < 4; ++j) glds16(srcA[j] + k0, &As[adof[j]]);
    glds16(srcB[0] + k0, &Bs[bdof[0]]);
    glds16(srcB[1] + k0, &Bs[bdof[1]]);
    __syncthreads();
#pragma unroll
    for (int kk = 0; kk < 2; ++kk) {
      s16x8 af[4], bq[4];
#pragma unroll
      for (int mi = 0; mi < 4; ++mi) {
        int rw = wr * 64 + mi * 16 + lr;
        af[mi] = *(const s16x8*)&As[rw * 64 + (((kk << 2) + lk) ^ (rw & 7)) * 8];
      }
#pragma unroll
      for (int ni = 0; ni < 4; ++ni) {
        int rn = wc * 64 + ni * 16 + lr;
        bq[ni] = *(const s16x8*)&Bs[rn * 64 + (((kk << 2) + lk) ^ (rn & 7)) * 8];
      }
      __builtin_amdgcn_s_setprio(1);
#pragma unroll
      for (int mi = 0; mi < 4; ++mi)
#pragma unroll
        for (int ni = 0; ni < 4; ++ni)
          acc[mi][ni] = __builtin_amdgcn_mfma_f32_16x16x32_bf16(af[mi], bq[ni], acc[mi][ni], 0, 0, 0);
      __builtin_amdgcn_s_setprio(0);
    }
  }

#pragma unroll
  for (int ni = 0; ni < 4; ++ni) {
    int col = wc * 64 + ni * 16 + lr;
    float bb = bg[col];
#pragma unroll
    for (int mi = 0; mi < 4; ++mi) {
      int rbase = row0 + wr * 64 + mi * 16 + lk * 4;
#pragma unroll
      for (int rr = 0; rr < 4; ++rr) {
        int gr = rbase + rr;
        if (gr < BATCH) {
          float x = acc[mi][ni][rr] + bb;
          float gate = 1.f / (1.f + __expf(-x));
          size_t vb = (size_t)(3 * gr) * 128 + col;
          float* po = &out[VECBASE + ((size_t)gr * 128 + col) * 3];
          po[0] = gate * bf2f(Vub[vb]);
          po[1] = gate * bf2f(Vub[vb + 128]);
          po[2] = gate * bf2f(Vub[vb + 256]);
        }
      }
    }
  }
}

// ---------------------------------------------------------------------------
extern "C" void kernel_launch(void* const* d_in, const int* in_sizes, int n_in,
                              void* d_out, int out_size, void* d_ws, size_t ws_size,
                              hipStream_t stream) {
  const float* feats = (const float*)d_in[0];
  const float* vecs  = (const float*)d_in[1];
  const float* Wh    = (const float*)d_in[2];
  const float* Wcp   = (const float*)d_in[3];
  const float* Wu    = (const float*)d_in[4];
  const float* Wf    = (const float*)d_in[5];
  const float* bfv   = (const float*)d_in[6];
  const float* Wg    = (const float*)d_in[7];
  const float* bg    = (const float*)d_in[8];
  float* out = (float*)d_out;

  char* ws = (char*)d_ws;
  short* Ab   = (short*)ws;                                // 140,800,000 B
  short* Vub  = (short*)(ws + 140800000);                  //  76,800,000 B
  short* fob  = (short*)(ws + 217600000);                  // 102,400,000 B
  short* WfT  = (short*)(ws + 320000000);                  //     720,896 B
  short* WgT  = (short*)(ws + 320720896);                  //     131,072 B
  short* WB1  = (short*)(ws + 320851968);                  //      40,960 B
  short* WuTp = (short*)(ws + 320892928);                  //      40,960 B

  hipLaunchKernelGGL(prep_w,     dim3(2048), dim3(256), 0, stream,
                     feats, Wh, Wcp, Wu, Wf, Wg, Ab, WB1, WuTp, WfT, WgT);
  hipLaunchKernelGGL(geo_fused,  dim3(1563), dim3(256), 0, stream,
                     vecs, WB1, WuTp, Ab, Vub);
  hipLaunchKernelGGL(gemm_feats, dim3(1564), dim3(512), 0, stream,
                     Ab, WfT, bfv, out, fob);
  hipLaunchKernelGGL(gemm_gate,  dim3(391),  dim3(512), 0, stream,
                     fob, WgT, bg, Vub, out);
}